// Round 12
// baseline (577.570 us; speedup 1.0000x reference)
//
#include <hip/hip_runtime.h>
#include <hip/hip_bf16.h>

#define NN 100000
#define EE 1600000

typedef unsigned short u16;
typedef unsigned int   u32;
typedef short short8 __attribute__((ext_vector_type(8)));
typedef float v4f    __attribute__((ext_vector_type(4)));
typedef u32 u32x2    __attribute__((ext_vector_type(2)));

__device__ __forceinline__ float b2f(u16 h){ u32 u = ((u32)h) << 16; return __builtin_bit_cast(float, u); }
__device__ __forceinline__ float lo2f(u32 u){ return __builtin_bit_cast(float, u << 16); }
__device__ __forceinline__ float hi2f(u32 u){ return __builtin_bit_cast(float, u & 0xffff0000u); }
__device__ __forceinline__ u16   f2b(float f){ __hip_bfloat16 h = __float2bfloat16(f); return __builtin_bit_cast(u16, h); }
__device__ __forceinline__ float ldx(const void* p, long i, int fm){
  return fm ? ((const float*)p)[i] : b2f(((const u16*)p)[i]);
}
__device__ __forceinline__ float i2f(int v){ return __builtin_bit_cast(float, v); }

// ---------------- weight packing + dtype detect + accum zero (fused) ----------------
// Wp[off + ((k>>3)*DOUT + col)*8 + (k&7)] = W[k*DOUT + col]
#define PW_G1 0        // Wg1 128x128
#define PW_G2 16384    // Wg2 128x32
#define PW_XY 20480    // Wxy 160x128
#define PW_XH 40960    // Wxh 128x128
#define PW_H2 57344    // Wh2 192x192
#define PW_HY 94208    // Why 192x32
#define PW_TOT 100352
#define PB_G1 0
#define PB_XY 128
#define PB_XH 256
#define PB_H2 384
#define PB_ZERO 576
#define PB_HY 704
#define PB_TOT 736

__global__ __launch_bounds__(256) void k_pack(const void* W0, const void* W1, const void* W2,
                      const void* W3, const void* W4, const void* W5,
                      const void* b0, const void* b1, const void* b2, const void* b3, const void* b4,
                      u16* __restrict__ Wp, float* __restrict__ bp,
                      const void* __restrict__ x, const void* __restrict__ nonlab,
                      int* __restrict__ flags, float* __restrict__ accum){
  __shared__ int s_bad, s_ni, s_nf, s_nb;
  int t = threadIdx.x;
  if (t == 0){ s_bad = 0; s_ni = 0; s_nf = 0; s_nb = 0; }
  __syncthreads();
  // every block self-detects fm from x's first 1KB (L2-hot)
  {
    u32 w = ((const u32*)x)[t];
    u32 lo = w & 0xffffu, ex = (lo >> 7) & 0xffu;
    if (lo != 0u && (ex < 100u || ex > 140u)) atomicAdd(&s_bad, 1);
  }
  if (blockIdx.x == 0){
    if (t < 64){
      u32 v = ((const u32*)nonlab)[t];
      if (v > 1u) atomicAdd(&s_ni, 1);
      if (v != 0u && v != 0x3F800000u) atomicAdd(&s_nf, 1);
    }
    if (t < 128){
      u16 h = ((const u16*)nonlab)[t];
      if (h != 0 && h != 0x3F80) atomicAdd(&s_nb, 1);
    }
  }
  __syncthreads();
  int fm = (s_bad > 32) ? 1 : 0;
  if (blockIdx.x == 0){
    if (t == 0){
      flags[0] = fm;
      flags[1] = (s_ni == 0) ? 1 : ((s_nf == 0) ? 3 : ((s_nb == 0) ? 2 : 0));
    }
    for (int i = t; i < 1024; i += 256) accum[i] = 0.f;   // zeroes colsum + bcnt regions
  }
  int e = blockIdx.x * 256 + t;
  if (e < PW_TOT){
    const void* src; int off, DOUT;
    if      (e < PW_G2){ src = W0; off = PW_G1; DOUT = 128; }
    else if (e < PW_XY){ src = W1; off = PW_G2; DOUT = 32; }
    else if (e < PW_XH){ src = W2; off = PW_XY; DOUT = 128; }
    else if (e < PW_H2){ src = W3; off = PW_XH; DOUT = 128; }
    else if (e < PW_HY){ src = W4; off = PW_H2; DOUT = 192; }
    else               { src = W5; off = PW_HY; DOUT = 32; }
    int local = e - off;
    int k = local / DOUT, col = local - k * DOUT;
    u16 v = fm ? f2b(((const float*)src)[local]) : ((const u16*)src)[local];
    Wp[off + ((k >> 3) * DOUT + col) * 8 + (k & 7)] = v;
  }
  int eb = e - PW_TOT;
  if (eb >= 0 && eb < PB_TOT){
    float v = 0.f;
    if      (eb < 128) v = ldx(b0, eb, fm);
    else if (eb < 256) v = ldx(b1, eb - 128, fm);
    else if (eb < 384) v = ldx(b2, eb - 256, fm);
    else if (eb < 576) v = ldx(b3, eb - 384, fm);
    else if (eb < 704) v = 0.f;
    else               v = ldx(b4, eb - 704, fm);
    bp[eb] = v;
  }
}

// ---------------- bucketed scatter constants ----------------
#define BSH 9
#define NBK 196     // ceil(NN / 512)
#define CAP 16384   // per-bucket staging capacity (mean 8192 for uniform data, +91 sigma)

// ---------------- mega-kernel: xp = x@Wg1 (blocks 0..1562)  ||  binA (blocks 1563..1953) ----
__global__ __launch_bounds__(256) void k_front(const void* __restrict__ x,
     const u16* __restrict__ Wg1p, u16* __restrict__ xpo, const int* __restrict__ flags,
     const int* __restrict__ ei, const void* __restrict__ ew,
     int* __restrict__ bcnt, int2* __restrict__ stage){
  if (blockIdx.x < 1563){
    constexpr int STEPS = 4, CT = 4, RTW = 2, G = 2;
    int wid = blockIdx.x * 4 + (threadIdx.x >> 6);
    if (wid >= 6250) return;
    int g = wid % G; long chunk = wid / G;
    int lane = threadIdx.x & 63, n = lane & 15, q = lane >> 4;
    int colOff = g * 64;
    int fm = flags[0];
    short8 B[CT][STEPS];
    #pragma unroll
    for (int ct = 0; ct < CT; ++ct){
      int col = colOff + ct * 16 + n;
      #pragma unroll
      for (int s = 0; s < STEPS; ++s)
        B[ct][s] = *(const short8*)(Wg1p + (((s * 4 + q) * 128) + col) * 8);
    }
    for (int rt = 0; rt < RTW; ++rt){
      long rowbase = (chunk * RTW + rt) * 16;
      long arow = rowbase + n;
      v4f acc[CT] = {};
      #pragma unroll
      for (int s = 0; s < STEPS; ++s){
        short8 a;
        long base = arow * 128 + s * 32 + q * 8;
        if (fm){
          const float* xp = (const float*)x + base;
          float4 x0 = *(const float4*)xp, x1 = *(const float4*)(xp + 4);
          a[0] = (short)f2b(x0.x); a[1] = (short)f2b(x0.y);
          a[2] = (short)f2b(x0.z); a[3] = (short)f2b(x0.w);
          a[4] = (short)f2b(x1.x); a[5] = (short)f2b(x1.y);
          a[6] = (short)f2b(x1.z); a[7] = (short)f2b(x1.w);
        } else {
          a = *(const short8*)((const u16*)x + base);
        }
        #pragma unroll
        for (int ct = 0; ct < CT; ++ct)
          acc[ct] = __builtin_amdgcn_mfma_f32_16x16x32_bf16(a, B[ct][s], acc[ct], 0, 0, 0);
      }
      long orow = rowbase + q * 4;
      #pragma unroll
      for (int ct = 0; ct < CT; ++ct){
        int col = colOff + ct * 16 + n;
        #pragma unroll
        for (int r = 0; r < 4; ++r)
          xpo[(orow + r) * 128 + col] = f2b(acc[ct][r]);
      }
    }
  } else {
    __shared__ int lcnt[NBK];
    __shared__ int lbase[NBK];
    int t = threadIdx.x;
    int bid = blockIdx.x - 1563;
    for (int i = t; i < NBK; i += 256) lcnt[i] = 0;
    __syncthreads();
    int fm = flags[0];
    long e0 = (long)bid * 4096;
    int bb[16], ord[16], pk[16], wb[16];
    #pragma unroll
    for (int j = 0; j < 16; ++j){
      long e = e0 + j * 256 + t;
      bool v = e < EE;
      int r = v ? ei[e] : 0;
      int c = v ? ei[EE + e] : 0;
      float w = v ? ldx(ew, e, fm) : 0.f;
      int b = r >> BSH;
      bb[j] = v ? b : -1;
      pk[j] = ((r & 511) << 17) | c;   // rowInBucket (9b) | col (17b)
      wb[j] = __builtin_bit_cast(int, w);
      if (v) ord[j] = atomicAdd(&lcnt[b], 1);
    }
    __syncthreads();
    for (int i = t; i < NBK; i += 256){
      int c = lcnt[i];
      lbase[i] = c ? atomicAdd(&bcnt[i], c) : 0;
    }
    __syncthreads();
    #pragma unroll
    for (int j = 0; j < 16; ++j){
      if (bb[j] >= 0){
        int pos = lbase[bb[j]] + ord[j];
        if (pos < CAP) stage[(long)bb[j] * CAP + pos] = make_int2(pk[j], wb[j]);
      }
    }
  }
}

// tiny exclusive scan of per-bucket totals -> bbase; rowptr[NN] = EE
__global__ void k_scanB(const int* __restrict__ bcnt, int* __restrict__ bbase,
                        int* __restrict__ rowptr){
  __shared__ int l[256];
  int t = threadIdx.x;
  int v = (t < NBK) ? bcnt[t] : 0;
  l[t] = v; __syncthreads();
  for (int o = 1; o < 256; o <<= 1){
    int x = (t >= o) ? l[t - o] : 0; __syncthreads();
    l[t] += x; __syncthreads();
  }
  if (t < NBK) bbase[t] = l[t] - v;
  if (t == 0) rowptr[NN] = EE;
}

// per-bucket: count rows, local scan -> rowptr, then exact-position scatter (L2-local)
__global__ __launch_bounds__(512) void k_binB(const int* __restrict__ bbase, const int* __restrict__ bcnt,
                      const int2* __restrict__ stage, int2* __restrict__ cpk,
                      int* __restrict__ rowptr){
  __shared__ int cnt[512];
  __shared__ int cur[512];
  int b = blockIdx.x, t = threadIdx.x;
  int r0 = b << BSH;
  int rows = min(512, NN - r0);
  cnt[t] = 0; __syncthreads();
  int cb = min(bcnt[b], CAP);
  const int2* sb = stage + (long)b * CAP;
  for (int j = t; j < cb; j += 512)
    atomicAdd(&cnt[((u32)sb[j].x) >> 17], 1);
  __syncthreads();
  int v = cnt[t];
  cur[t] = v; __syncthreads();
  for (int o = 1; o < 512; o <<= 1){
    int x = (t >= o) ? cur[t - o] : 0; __syncthreads();
    cur[t] += x; __syncthreads();
  }
  int excl = bbase[b] + cur[t] - v;
  if (t < rows) rowptr[r0 + t] = excl;
  __syncthreads();
  cur[t] = excl;
  __syncthreads();
  for (int j = t; j < cb; j += 512){
    int2 w = sb[j];
    int rib = ((u32)w.x) >> 17;
    int pos = atomicAdd(&cur[rib], 1);
    cpk[pos] = make_int2(w.x & 0x1FFFF, w.y);
  }
}

// ---------------- S1 SpMM D=128 + fused yproj epilogue (16 rows/block, 1024 thr) ----------------
// Each wave gathers one row (paired-edge), writes relu(spmm+bg1) to out AND LDS; wave 0 then
// computes yproj[16,32] = hl @ Wg2 via MFMA. NN = 6250*16 exactly.
__global__ __launch_bounds__(1024) void k_spmmyp(const u16* __restrict__ in, u16* __restrict__ out,
                       const int* __restrict__ rowptr, const int2* __restrict__ cpk,
                       const float* __restrict__ bias, const u16* __restrict__ Wg2p,
                       u16* __restrict__ yproj){
  __shared__ u16 hl[16][136];   // pad 8: row stride 272B (17x16B) -> benign 2-way conflicts
  int w = threadIdx.x >> 6;
  int wid = blockIdx.x * 16 + w;
  int lane = threadIdx.x & 63;
  int half = lane >> 5, l16 = lane & 31;
  int s = rowptr[wid], e = rowptr[wid + 1];
  float a0 = 0.f, a1 = 0.f, a2 = 0.f, a3 = 0.f;
  for (int j = s; j < e; j += 8){
    int2 pe[4];
    if (j + 8 <= e){
      #pragma unroll
      for (int k = 0; k < 4; ++k) pe[k] = cpk[j + 2 * k + half];
    } else {
      #pragma unroll
      for (int k = 0; k < 4; ++k){
        int idx = j + 2 * k + half;
        int2 ww = cpk[idx < e ? idx : j];
        if (idx >= e) ww.y = 0;
        pe[k] = ww;
      }
    }
    u32x2 u[4];
    #pragma unroll
    for (int k = 0; k < 4; ++k)
      u[k] = *(const u32x2*)(in + (long)pe[k].x * 128 + 4 * l16);
    #pragma unroll
    for (int k = 0; k < 4; ++k){
      float wt = i2f(pe[k].y);
      a0 = fmaf(wt, lo2f(u[k].x), a0);
      a1 = fmaf(wt, hi2f(u[k].x), a1);
      a2 = fmaf(wt, lo2f(u[k].y), a2);
      a3 = fmaf(wt, hi2f(u[k].y), a3);
    }
  }
  a0 += __shfl_xor(a0, 32); a1 += __shfl_xor(a1, 32);
  a2 += __shfl_xor(a2, 32); a3 += __shfl_xor(a3, 32);
  a0 = fmaxf(a0 + bias[4 * l16],     0.f);
  a1 = fmaxf(a1 + bias[4 * l16 + 1], 0.f);
  a2 = fmaxf(a2 + bias[4 * l16 + 2], 0.f);
  a3 = fmaxf(a3 + bias[4 * l16 + 3], 0.f);
  if (half == 0){
    u32x2 wv;
    wv.x = (u32)f2b(a0) | ((u32)f2b(a1) << 16);
    wv.y = (u32)f2b(a2) | ((u32)f2b(a3) << 16);
    *(u32x2*)(out + (long)wid * 128 + 4 * l16) = wv;
    *(u32x2*)(&hl[w][4 * l16]) = wv;
  }
  __syncthreads();
  if (w == 0){
    int n = lane & 15, q = lane >> 4;
    short8 B[2][4];
    #pragma unroll
    for (int ct = 0; ct < 2; ++ct){
      int col = ct * 16 + n;
      #pragma unroll
      for (int s2 = 0; s2 < 4; ++s2)
        B[ct][s2] = *(const short8*)(Wg2p + (((s2 * 4 + q) * 32) + col) * 8);
    }
    v4f acc[2] = {};
    #pragma unroll
    for (int s2 = 0; s2 < 4; ++s2){
      short8 a = *(const short8*)(&hl[n][s2 * 32 + q * 8]);
      #pragma unroll
      for (int ct = 0; ct < 2; ++ct)
        acc[ct] = __builtin_amdgcn_mfma_f32_16x16x32_bf16(a, B[ct][s2], acc[ct], 0, 0, 0);
    }
    long rowbase = (long)blockIdx.x * 16;
    #pragma unroll
    for (int ct = 0; ct < 2; ++ct){
      int col = ct * 16 + n;
      #pragma unroll
      for (int r = 0; r < 4; ++r)
        yproj[(rowbase + q * 4 + r) * 32 + col] = f2b(acc[ct][r]);
    }
  }
}

// ---------------- SpMM D=128: one wave per row, paired-edge gather (S3) ----------------
template<bool AG, bool EPI>
__global__ __launch_bounds__(256) void k_spmm(const u16* __restrict__ in, u16* __restrict__ out,
                       const int* __restrict__ rowptr, const int2* __restrict__ cpk,
                       const float* __restrict__ agt, float* __restrict__ agg,
                       const float* __restrict__ bias){
  int wid  = blockIdx.x * 4 + (threadIdx.x >> 6);
  int lane = threadIdx.x & 63;
  if (wid >= NN) return;
  int half = lane >> 5, l16 = lane & 31;
  int s = rowptr[wid], e = rowptr[wid + 1];
  float a0 = 0.f, a1 = 0.f, a2 = 0.f, a3 = 0.f, aga = 0.f;
  for (int j = s; j < e; j += 8){
    int2 pe[4];
    if (j + 8 <= e){
      #pragma unroll
      for (int k = 0; k < 4; ++k) pe[k] = cpk[j + 2 * k + half];
    } else {
      #pragma unroll
      for (int k = 0; k < 4; ++k){
        int idx = j + 2 * k + half;
        int2 w = cpk[idx < e ? idx : j];
        if (idx >= e) w.y = 0;           // weight 0 -> fmaf no-op, bit-exact
        pe[k] = w;
      }
    }
    u32x2 u[4];
    #pragma unroll
    for (int k = 0; k < 4; ++k)
      u[k] = *(const u32x2*)(in + (long)pe[k].x * 128 + 4 * l16);
    if (AG && l16 == 0){
      #pragma unroll
      for (int k = 0; k < 4; ++k) aga = fmaf(i2f(pe[k].y), agt[pe[k].x], aga);
    }
    #pragma unroll
    for (int k = 0; k < 4; ++k){
      float wt = i2f(pe[k].y);
      a0 = fmaf(wt, lo2f(u[k].x), a0);
      a1 = fmaf(wt, hi2f(u[k].x), a1);
      a2 = fmaf(wt, lo2f(u[k].y), a2);
      a3 = fmaf(wt, hi2f(u[k].y), a3);
    }
  }
  a0 += __shfl_xor(a0, 32); a1 += __shfl_xor(a1, 32);
  a2 += __shfl_xor(a2, 32); a3 += __shfl_xor(a3, 32);
  if (AG) aga += __shfl_xor(aga, 32);
  if (EPI){
    a0 = fmaxf(a0 + bias[4 * l16],     0.f);
    a1 = fmaxf(a1 + bias[4 * l16 + 1], 0.f);
    a2 = fmaxf(a2 + bias[4 * l16 + 2], 0.f);
    a3 = fmaxf(a3 + bias[4 * l16 + 3], 0.f);
  }
  if (half == 0){
    u32x2 w;
    w.x = (u32)f2b(a0) | ((u32)f2b(a1) << 16);
    w.y = (u32)f2b(a2) | ((u32)f2b(a3) << 16);
    *(u32x2*)(out + (long)wid * 128 + 4 * l16) = w;
    if (AG && l16 == 0) agg[wid] = aga;
  }
}

// ---------------- SpMM D=32 bf16-table + f32 bias -> y_pred (paired-edge: 8 lanes x 8B) ----------------
__global__ __launch_bounds__(256) void k_spmm32b(const u16* __restrict__ in, void* __restrict__ out,
                       const int* __restrict__ rowptr, const int2* __restrict__ cpk,
                       const int* __restrict__ flags, const float* __restrict__ bp){
  int row = blockIdx.x * 16 + (threadIdx.x >> 4);
  int d = threadIdx.x & 15;
  if (row >= NN) return;
  int eh = d >> 3, d8 = d & 7;
  int fm = flags[0];
  int s = rowptr[row], e = rowptr[row + 1];
  float a0 = 0.f, a1 = 0.f, a2 = 0.f, a3 = 0.f;
  for (int j = s; j < e; j += 8){
    int2 p[4];
    if (j + 8 <= e){
      #pragma unroll
      for (int k = 0; k < 4; ++k) p[k] = cpk[j + 2 * k + eh];
    } else {
      #pragma unroll
      for (int k = 0; k < 4; ++k){
        int idx = j + 2 * k + eh;
        int2 w = cpk[idx < e ? idx : j];
        if (idx >= e) w.y = 0;
        p[k] = w;
      }
    }
    u32x2 u[4];
    #pragma unroll
    for (int k = 0; k < 4; ++k) u[k] = *(const u32x2*)(in + (long)p[k].x * 32 + 4 * d8);
    #pragma unroll
    for (int k = 0; k < 4; ++k){
      float wt = i2f(p[k].y);
      a0 = fmaf(wt, lo2f(u[k].x), a0);
      a1 = fmaf(wt, hi2f(u[k].x), a1);
      a2 = fmaf(wt, lo2f(u[k].y), a2);
      a3 = fmaf(wt, hi2f(u[k].y), a3);
    }
  }
  a0 += __shfl_xor(a0, 8); a1 += __shfl_xor(a1, 8);
  a2 += __shfl_xor(a2, 8); a3 += __shfl_xor(a3, 8);
  a0 += bp[4 * d8]; a1 += bp[4 * d8 + 1]; a2 += bp[4 * d8 + 2]; a3 += bp[4 * d8 + 3];
  if (eh == 0){
    if (fm){
      float4 w = make_float4(a0, a1, a2, a3);
      *(float4*)((float*)out + (long)row * 32 + 4 * d8) = w;
    } else {
      u32x2 w;
      w.x = (u32)f2b(a0) | ((u32)f2b(a1) << 16);
      w.y = (u32)f2b(a2) | ((u32)f2b(a3) << 16);
      *(u32x2*)((u16*)out + (long)row * 32 + 4 * d8) = w;
    }
  }
}

// ---------------- SpMM D=32 + gumbel/where -> y (paired-edge; skips labelled rows) ----------------
__global__ __launch_bounds__(256) void k_spmmg(const u16* __restrict__ in, u16* __restrict__ y,
                       const int* __restrict__ rowptr, const int2* __restrict__ cpk,
                       const int* __restrict__ flags, const void* __restrict__ bg2,
                       const void* __restrict__ ug, const void* __restrict__ ylab,
                       const void* __restrict__ nonlab){
  int row = blockIdx.x * 16 + (threadIdx.x >> 4);
  int d = threadIdx.x & 15;
  if (row >= NN) return;
  int fm = flags[0], mode = flags[1];
  bool nl;
  if      (mode == 1) nl = ((const int*)nonlab)[row] != 0;
  else if (mode == 3) nl = ((const float*)nonlab)[row] != 0.f;
  else if (mode == 2) nl = ((const u16*)nonlab)[row] != 0;
  else                nl = ((const unsigned char*)nonlab)[row] != 0;
  long base = (long)row * 32;
  if (!nl){
    u32 lo, hi;
    if (fm){
      lo = (u32)f2b(((const float*)ylab)[base + 2 * d]);
      hi = (u32)f2b(((const float*)ylab)[base + 2 * d + 1]);
    } else {
      lo = ((const u16*)ylab)[base + 2 * d];
      hi = ((const u16*)ylab)[base + 2 * d + 1];
    }
    *(u32*)(y + base + 2 * d) = lo | (hi << 16);
    return;
  }
  int eh = d >> 3, d8 = d & 7;
  int s = rowptr[row], e = rowptr[row + 1];
  float a0 = 0.f, a1 = 0.f, a2 = 0.f, a3 = 0.f;
  for (int j = s; j < e; j += 8){
    int2 p[4];
    if (j + 8 <= e){
      #pragma unroll
      for (int k = 0; k < 4; ++k) p[k] = cpk[j + 2 * k + eh];
    } else {
      #pragma unroll
      for (int k = 0; k < 4; ++k){
        int idx = j + 2 * k + eh;
        int2 w = cpk[idx < e ? idx : j];
        if (idx >= e) w.y = 0;
        p[k] = w;
      }
    }
    u32x2 u[4];
    #pragma unroll
    for (int k = 0; k < 4; ++k) u[k] = *(const u32x2*)(in + (long)p[k].x * 32 + 4 * d8);
    #pragma unroll
    for (int k = 0; k < 4; ++k){
      float wt = i2f(p[k].y);
      a0 = fmaf(wt, lo2f(u[k].x), a0);
      a1 = fmaf(wt, hi2f(u[k].x), a1);
      a2 = fmaf(wt, lo2f(u[k].y), a2);
      a3 = fmaf(wt, hi2f(u[k].y), a3);
    }
  }
  a0 += __shfl_xor(a0, 8); a1 += __shfl_xor(a1, 8);
  a2 += __shfl_xor(a2, 8); a3 += __shfl_xor(a3, 8);
  float av[4] = {a0, a1, a2, a3};
  int c0 = 4 * d8;
  float bm = -1e30f; int bi = 0;
  #pragma unroll
  for (int jj = 0; jj < 4; ++jj){
    float uu = ldx(ug, base + c0 + jj, fm);
    float g = -logf(-logf(uu + 1e-10f) + 1e-10f);
    float v = av[jj] + ldx(bg2, c0 + jj, fm) + g;
    if (v > bm){ bm = v; bi = c0 + jj; }    // strict > keeps first max
  }
  #pragma unroll
  for (int o = 1; o < 16; o <<= 1){
    float om = __shfl_xor(bm, o);
    int   oi = __shfl_xor(bi, o);
    if (om > bm || (om == bm && oi < bi)){ bm = om; bi = oi; }
  }
  if (eh == 0){
    u32x2 w;
    w.x = ((c0     == bi) ? 0x3F80u : 0u) | (((c0 + 1 == bi) ? 0x3F80u : 0u) << 16);
    w.y = ((c0 + 2 == bi) ? 0x3F80u : 0u) | (((c0 + 3 == bi) ? 0x3F80u : 0u) << 16);
    *(u32x2*)(y + base + c0) = w;
  }
}

// ---------------- generic MFMA GEMM (packed weights) ----------------
// AMODE 0: A[N,K]; 2: concat(A[N,128], A2[N,32])
// OMODE 0: bf16 out; 3: no store. CSUM: per-block column sums -> pb[blockIdx][128]
template<int K, int DOUT, int CT, int RTW, bool RELU, int AMODE, int OMODE, bool CSUM>
__global__ __launch_bounds__(256) void k_mm(const u16* __restrict__ A, const void* __restrict__ A2,
     const void* __restrict__ A3, const u16* __restrict__ Wp, const float* __restrict__ bp,
     void* __restrict__ outv, const int* __restrict__ flags, float* __restrict__ csacc){
  constexpr int STEPS = K / 32;
  constexpr int G = DOUT / (16 * CT);
  constexpr int CHUNKS = 6250 / RTW;      // N = 6250 * 16 exactly
  __shared__ float lsum[128];
  int wid = blockIdx.x * 4 + (threadIdx.x >> 6);
  if (wid >= G * CHUNKS) return;          // wave-uniform exit
  int g = wid % G; long chunk = wid / G;
  int lane = threadIdx.x & 63, n = lane & 15, q = lane >> 4;
  int colOff = g * CT * 16;

  if (CSUM){
    if (threadIdx.x < 128) lsum[threadIdx.x] = 0.f;
    __syncthreads();
  }

  short8 B[CT][STEPS];
  float bv[CT];
  #pragma unroll
  for (int ct = 0; ct < CT; ++ct){
    int col = colOff + ct * 16 + n;
    bv[ct] = bp[col];
    #pragma unroll
    for (int s = 0; s < STEPS; ++s)
      B[ct][s] = *(const short8*)(Wp + (((s * 4 + q) * DOUT) + col) * 8);
  }

  float csum[CT];
  #pragma unroll
  for (int ct = 0; ct < CT; ++ct) csum[ct] = 0.f;

  for (int rt = 0; rt < RTW; ++rt){
    long rowbase = (chunk * RTW + rt) * 16;
    long arow = rowbase + n;
    v4f acc[CT] = {};
    #pragma unroll
    for (int s = 0; s < STEPS; ++s){
      short8 a;
      if (AMODE == 0){
        a = *(const short8*)(A + arow * K + s * 32 + q * 8);
      } else { // AMODE==2: concat(hemb[N,128], y[N,32]), K=160
        if (s < 4) a = *(const short8*)(A + arow * 128 + s * 32 + q * 8);
        else       a = *(const short8*)((const u16*)A2 + arow * 32 + q * 8);
      }
      #pragma unroll
      for (int ct = 0; ct < CT; ++ct)
        acc[ct] = __builtin_amdgcn_mfma_f32_16x16x32_bf16(a, B[ct][s], acc[ct], 0, 0, 0);
    }
    long orow = rowbase + q * 4;
    #pragma unroll
    for (int ct = 0; ct < CT; ++ct){
      int col = colOff + ct * 16 + n;
      #pragma unroll
      for (int r = 0; r < 4; ++r){
        float v = acc[ct][r] + bv[ct];
        if (RELU) v = fmaxf(v, 0.f);
        if (CSUM) csum[ct] += v;
        if (OMODE != 3){
          long oi = (orow + r) * (long)DOUT + col;
          ((u16*)outv)[oi] = f2b(v);
        }
      }
    }
  }
  if (CSUM){
    #pragma unroll
    for (int ct = 0; ct < CT; ++ct){
      csum[ct] += __shfl_xor(csum[ct], 16);
      csum[ct] += __shfl_xor(csum[ct], 32);
      if (lane < 16) atomicAdd(&lsum[colOff + ct * 16 + n], csum[ct]);
    }
    __syncthreads();
    if (threadIdx.x < 128) csacc[(long)blockIdx.x * 128 + threadIdx.x] = lsum[threadIdx.x];
  }
}

// ---------------- fused h2 GEMM + (h2 @ Why) via LDS: never materializes h2 ----------------
__global__ __launch_bounds__(256) void k_mmh2(const u16* __restrict__ A, const float* __restrict__ AG2,
     const float* __restrict__ zbuf, const u16* __restrict__ Wh2p, const float* __restrict__ bh2p,
     const u16* __restrict__ Whyp, u16* __restrict__ tbuf){
  __shared__ u16 hl[16][200];   // 16x192 bf16 tile, row stride 200 (400B) to break bank conflicts
  int w = threadIdx.x >> 6;
  int lane = threadIdx.x & 63, n = lane & 15, q = lane >> 4;
  int colOff = w * 48;          // 4 waves x CT=3 x 16 = 192 cols

  short8 B[3][6];
  float bv[3];
  #pragma unroll
  for (int ct = 0; ct < 3; ++ct){
    int col = colOff + ct * 16 + n;
    bv[ct] = bh2p[col];
    #pragma unroll
    for (int s = 0; s < 6; ++s)
      B[ct][s] = *(const short8*)(Wh2p + (((s * 4 + q) * 192) + col) * 8);
  }
  short8 B2[2][6];
  if (w == 0){
    #pragma unroll
    for (int ct = 0; ct < 2; ++ct){
      int col = ct * 16 + n;
      #pragma unroll
      for (int s = 0; s < 6; ++s)
        B2[ct][s] = *(const short8*)(Whyp + (((s * 4 + q) * 32) + col) * 8);
    }
  }

  for (int rt = 0; rt < 2; ++rt){
    long rowbase = ((long)blockIdx.x * 2 + rt) * 16;
    long arow = rowbase + n;
    float agr = AG2[arow];
    v4f acc[3] = {};
    #pragma unroll
    for (int s = 0; s < 6; ++s){
      short8 a;
      if (s < 4) a = *(const short8*)(A + arow * 128 + s * 32 + q * 8);
      else {
        #pragma unroll
        for (int j = 0; j < 8; ++j) a[j] = (short)f2b(agr * zbuf[(s - 4) * 32 + q * 8 + j]);
      }
      #pragma unroll
      for (int ct = 0; ct < 3; ++ct)
        acc[ct] = __builtin_amdgcn_mfma_f32_16x16x32_bf16(a, B[ct][s], acc[ct], 0, 0, 0);
    }
    #pragma unroll
    for (int ct = 0; ct < 3; ++ct){
      int col = colOff + ct * 16 + n;
      #pragma unroll
      for (int r = 0; r < 4; ++r)
        hl[q * 4 + r][col] = f2b(fmaxf(acc[ct][r] + bv[ct], 0.f));
    }
    __syncthreads();
    if (w == 0){
      v4f a2[2] = {};
      #pragma unroll
      for (int s = 0; s < 6; ++s){
        short8 a = *(const short8*)(&hl[n][s * 32 + q * 8]);
        #pragma unroll
        for (int ct = 0; ct < 2; ++ct)
          a2[ct] = __builtin_amdgcn_mfma_f32_16x16x32_bf16(a, B2[ct][s], a2[ct], 0, 0, 0);
      }
      #pragma unroll
      for (int ct = 0; ct < 2; ++ct){
        int col = ct * 16 + n;
        #pragma unroll
        for (int r = 0; r < 4; ++r)
          tbuf[(rowbase + q * 4 + r) * 32 + col] = f2b(a2[ct][r]);
      }
    }
    __syncthreads();
  }
}

// ---------------- reduce per-block colsum partials: pb[1563][128] -> accum[128] ----------------
__global__ __launch_bounds__(256) void k_csred(const float* __restrict__ pb, float* __restrict__ accum){
  __shared__ float l[256];
  int c = blockIdx.x, t = threadIdx.x;
  float s = 0.f;
  for (int r = t; r < 1563; r += 256) s += pb[(long)r * 128 + c];
  l[t] = s; __syncthreads();
  for (int o = 128; o; o >>= 1){ if (t < o) l[t] += l[t + o]; __syncthreads(); }
  if (t == 0) accum[c] = l[0];
}

// ---------------- fused (x*dm)@Wxh -> relu -> row-normalize with z -> Hs, AG1 ----------------
__global__ __launch_bounds__(256) void k_mmnorm(const void* __restrict__ A2, const void* __restrict__ A3,
     const u16* __restrict__ Wp, const float* __restrict__ bp,
     u16* __restrict__ outHs, float* __restrict__ ag,
     const float* __restrict__ zbuf, const int* __restrict__ flags){
  constexpr int STEPS = 4, CT = 8, CHUNKS = 6250;   // RTW=1
  int wid = blockIdx.x * 4 + (threadIdx.x >> 6);
  if (wid >= CHUNKS) return;
  long chunk = wid;
  int lane = threadIdx.x & 63, n = lane & 15, q = lane >> 4;
  int fm = flags[0];

  short8 B[CT][STEPS];
  float bv[CT];
  #pragma unroll
  for (int ct = 0; ct < CT; ++ct){
    int col = ct * 16 + n;
    bv[ct] = bp[col];
    #pragma unroll
    for (int s = 0; s < STEPS; ++s)
      B[ct][s] = *(const short8*)(Wp + (((s * 4 + q) * 128) + col) * 8);
  }
  float zz = zbuf[64];

  {
    long rowbase = chunk * 16;
    long arow = rowbase + n;
    v4f acc[CT] = {};
    #pragma unroll
    for (int s = 0; s < STEPS; ++s){
      short8 a;
      long base = arow * 128 + s * 32 + q * 8;
      if (fm){
        const float* xp = (const float*)A2 + base;
        const float* dp = (const float*)A3 + base;
        float4 x0 = *(const float4*)xp, x1 = *(const float4*)(xp + 4);
        float4 d0 = *(const float4*)dp, d1 = *(const float4*)(dp + 4);
        a[0] = (short)f2b(x0.x * d0.x); a[1] = (short)f2b(x0.y * d0.y);
        a[2] = (short)f2b(x0.z * d0.z); a[3] = (short)f2b(x0.w * d0.w);
        a[4] = (short)f2b(x1.x * d1.x); a[5] = (short)f2b(x1.y * d1.y);
        a[6] = (short)f2b(x1.z * d1.z); a[7] = (short)f2b(x1.w * d1.w);
      } else {
        short8 xv = *(const short8*)((const u16*)A2 + base);
        short8 dv = *(const short8*)((const u16*)A3 + base);
        #pragma unroll
        for (int j = 0; j < 8; ++j) a[j] = (short)f2b(b2f((u16)xv[j]) * b2f((u16)dv[j]));
      }
      #pragma unroll
      for (int ct = 0; ct < CT; ++ct)
        acc[ct] = __builtin_amdgcn_mfma_f32_16x16x32_bf16(a, B[ct][s], acc[ct], 0, 0, 0);
    }
    // relu + row-norm epilogue
    float v[CT][4];
    float sqr[4] = {0.f, 0.f, 0.f, 0.f};
    #pragma unroll
    for (int ct = 0; ct < CT; ++ct){
      #pragma unroll
      for (int r = 0; r < 4; ++r){
        float t = fmaxf(acc[ct][r] + bv[ct], 0.f);
        v[ct][r] = t;
        sqr[r] += t * t;
      }
    }
    #pragma unroll
    for (int r = 0; r < 4; ++r){
      #pragma unroll
      for (int o = 1; o < 16; o <<= 1) sqr[r] += __shfl_xor(sqr[r], o);
    }
    float scale[4];
    #pragma unroll
    for (int r = 0; r < 4; ++r) scale[r] = 1.f / (sqrtf(sqr[r] + zz) + 1e-6f);
    long orow = rowbase + q * 4;
    #pragma unroll
    for (int ct = 0; ct < CT; ++ct){
      int col = ct * 16 + n;
      #pragma unroll
      for (int r = 0; r < 4; ++r)
        outHs[(orow + r) * 128 + col] = f2b(v[ct][r] * scale[r]);
    }
    if (n == 0){
      #pragma unroll
      for (int r = 0; r < 4; ++r) ag[orow + r] = scale[r];
    }
  }
}

// ---------------- tiny tail: r_graph -> hr -> mu/sigma -> z, plus ||z||^2 ----------------
__global__ void k_z(const float* __restrict__ accum,
                    const void* Whr, const void* bhr, const void* Wrh, const void* brh,
                    const void* Wmu, const void* bmu, const void* Wsig, const void* bsig,
                    const void* zeps, float* __restrict__ zout, const int* __restrict__ flags){
  __shared__ float hm[128], rg[128], hr[128], zl[64];
  int t = threadIdx.x, fm = flags[0];
  hm[t] = accum[t] * (1.0f / 100000.0f);
  __syncthreads();
  { float s = ldx(bhr, t, fm);
    for (int k = 0; k < 128; ++k) s = fmaf(hm[k], ldx(Whr, (long)k * 128 + t, fm), s);
    rg[t] = s; }
  __syncthreads();
  { float s = ldx(brh, t, fm);
    for (int k = 0; k < 128; ++k) s = fmaf(rg[k], ldx(Wrh, (long)k * 128 + t, fm), s);
    hr[t] = fmaxf(s, 0.f); }
  __syncthreads();
  if (t < 64){
    float m = ldx(bmu, t, fm), sv = ldx(bsig, t, fm);
    for (int k = 0; k < 128; ++k){
      float h = hr[k];
      m  = fmaf(h, ldx(Wmu,  (long)k * 64 + t, fm), m);
      sv = fmaf(h, ldx(Wsig, (long)k * 64 + t, fm), sv);
    }
    float sig = 0.1f + 0.9f / (1.f + expf(-sv));
    float z = fmaf(sig, ldx(zeps, t, fm), m);
    zl[t] = z; zout[t] = z;
  }
  __syncthreads();
  if (t == 0){ float ss = 0.f; for (int j = 0; j < 64; ++j) ss += zl[j] * zl[j]; zout[64] = ss; }
}

extern "C" void kernel_launch(void* const* d_in, const int* in_sizes, int n_in,
                              void* d_out, int out_size, void* d_ws, size_t ws_size,
                              hipStream_t stream){
  const void* x    = d_in[0];
  const void* ylab = d_in[1];
  const int*  ei   = (const int*)d_in[2];
  const void* ew   = d_in[3];
  const void* nonlab = d_in[4];
  const void* dm   = d_in[5];
  const void* ug   = d_in[6];
  const void* zeps = d_in[7];
  const void* Wg1 = d_in[8],  *bg1 = d_in[9];
  const void* Wg2 = d_in[10], *bg2 = d_in[11];
  const void* Wxy = d_in[12], *bxy = d_in[13];
  const void* Whr = d_in[14], *bhr = d_in[15];
  const void* Wrh = d_in[16], *brh = d_in[17];
  const void* Wmu = d_in[18], *bmu = d_in[19];
  const void* Wsg = d_in[20], *bsg = d_in[21];
  const void* Wxh = d_in[22], *bxh = d_in[23];
  const void* Wh2 = d_in[24], *bh2 = d_in[25];
  const void* Why = d_in[26], *bhy = d_in[27];

  char* ws = (char*)d_ws;
  size_t off = 0;
  auto alloc = [&](size_t bytes){ void* p = ws + off; off += (bytes + 511) & ~(size_t)511; return p; };
  int*   flags  = (int*)  alloc(256);
  int*   rowptr = (int*)  alloc((size_t)(NN + 1) * 4);
  int*   bbase  = (int*)  alloc(1024 * 4);
  float* accum  = (float*)alloc(1024 * 4);   // [0:128) colsum, [128:192) z, [192] ||z||^2, [512:708) bcnt
  u16*   Wpack  = (u16*)  alloc((size_t)PW_TOT * 2);
  float* bpack  = (float*)alloc((size_t)PB_TOT * 4);
  float* AG1    = (float*)alloc((size_t)NN * 4);   // per-row norm scale
  float* AG2    = (float*)alloc((size_t)NN * 4);   // spmm of scale
  float* pb     = (float*)alloc((size_t)1563 * 128 * 4);  // per-block colsum partials
  int2*  cpk    = (int2*) alloc((size_t)EE * 8);
  u16*   B0     = (u16*)  alloc((size_t)NN * 192 * 2);
  u16*   B1     = (u16*)  alloc((size_t)NN * 192 * 2);
  // layout: stage=B0 (dead after binB); xp=B1[0:128] (dead after S1); h_emb=B0[0:128];
  // yproj=B0[128:160); ybuf=B1[160:192); Hs=B1[0:128]; tbuf(bf16)=B1[0:32) (B0 live as spmmH!)
  u16* yproj = B0 + (size_t)NN * 128;   // [N,32] bf16 (h_emb @ Wg2)
  u16* ybuf  = B1 + (size_t)NN * 160;   // [N,32] bf16 (y)
  int2* stage = (int2*)B0;
  u16* tbuf = B1;                       // [N,32] bf16 (h2 @ Why) -- B1 free after S3 consumed Hs
  int* bcnt = (int*)(accum + 512);      // NBK per-bucket staged counts (zeroed by k_pack)

  // pack (+detect +accum zero) -- must precede everything that reads flags/bcnt/Wpack
  k_pack<<<(PW_TOT + PB_TOT + 255) / 256, 256, 0, stream>>>(Wg1, Wg2, Wxy, Wxh, Wh2, Why,
                                                            bg1, bxy, bxh, bh2, bhy, Wpack, bpack,
                                                            x, nonlab, flags, accum);
  // mega-kernel: xp GEMM (1563 blocks) overlapped with binA (391 blocks)
  k_front<<<1954, 256, 0, stream>>>(x, Wpack + PW_G1, B1, flags, ei, ew, bcnt, stage);
  k_scanB<<<1, 256, 0, stream>>>(bcnt, bbase, rowptr);
  k_binB <<<NBK, 512, 0, stream>>>(bbase, bcnt, stage, cpk, rowptr);
  // pipeline
  k_spmmyp<<<6250, 1024, 0, stream>>>(B1, B0, rowptr, cpk, bpack + PB_G1, Wpack + PW_G2, yproj); // S1 + yproj
  k_spmmg<<<6250, 256, 0, stream>>>(yproj, ybuf, rowptr, cpk, flags, bg2, ug, ylab, nonlab);     // S2'+gumbel -> y
  k_mm<160,128,4,2,true ,2,3,true ><<<1563, 256, 0, stream>>>(B0, ybuf, nullptr, Wpack + PW_XY, bpack + PB_XY, nullptr, flags, pb); // colsum partials
  k_csred<<<128, 256, 0, stream>>>(pb, accum);                                                   // reduce -> accum[0:128)
  k_z<<<1, 128, 0, stream>>>(accum, Whr, bhr, Wrh, brh, Wmu, bmu, Wsg, bsg, zeps, accum + 128, flags);
  k_mmnorm<<<1563, 256, 0, stream>>>(x, dm, Wpack + PW_XH, bpack + PB_XH, B1, AG1, accum + 128, flags); // Hs->B1, AG1
  k_spmm<true ,false><<<25000, 256, 0, stream>>>(B1, B0, rowptr, cpk, AG1, AG2, nullptr);        // S3: Hs->B0, agg->AG2
  k_mmh2<<<3125, 256, 0, stream>>>(B0, AG2, accum + 128, Wpack + PW_H2, bpack + PB_H2,
                                   Wpack + PW_HY, tbuf);                                         // fused h2+Why -> tbuf (B1)
  k_spmm32b<<<6250, 256, 0, stream>>>(tbuf, d_out, rowptr, cpk, flags, bpack + PB_HY);           // S4': y_pred
}

// Round 13
// 568.024 us; speedup vs baseline: 1.0168x; 1.0168x over previous
//
#include <hip/hip_runtime.h>
#include <hip/hip_bf16.h>

#define NN 100000
#define EE 1600000

typedef unsigned short u16;
typedef unsigned int   u32;
typedef short short8 __attribute__((ext_vector_type(8)));
typedef float v4f    __attribute__((ext_vector_type(4)));
typedef u32 u32x2    __attribute__((ext_vector_type(2)));

__device__ __forceinline__ float b2f(u16 h){ u32 u = ((u32)h) << 16; return __builtin_bit_cast(float, u); }
__device__ __forceinline__ float lo2f(u32 u){ return __builtin_bit_cast(float, u << 16); }
__device__ __forceinline__ float hi2f(u32 u){ return __builtin_bit_cast(float, u & 0xffff0000u); }
__device__ __forceinline__ u16   f2b(float f){ __hip_bfloat16 h = __float2bfloat16(f); return __builtin_bit_cast(u16, h); }
__device__ __forceinline__ float ldx(const void* p, long i, int fm){
  return fm ? ((const float*)p)[i] : b2f(((const u16*)p)[i]);
}
__device__ __forceinline__ float i2f(int v){ return __builtin_bit_cast(float, v); }

// ---------------- weight packing + dtype detect + accum zero (fused) ----------------
// Wp[off + ((k>>3)*DOUT + col)*8 + (k&7)] = W[k*DOUT + col]
#define PW_G1 0        // Wg1 128x128
#define PW_G2 16384    // Wg2 128x32
#define PW_XY 20480    // Wxy 160x128
#define PW_XH 40960    // Wxh 128x128
#define PW_H2 57344    // Wh2 192x192
#define PW_HY 94208    // Why 192x32
#define PW_TOT 100352
#define PB_G1 0
#define PB_XY 128
#define PB_XH 256
#define PB_H2 384
#define PB_ZERO 576
#define PB_HY 704
#define PB_TOT 736

__global__ __launch_bounds__(256) void k_pack(const void* W0, const void* W1, const void* W2,
                      const void* W3, const void* W4, const void* W5,
                      const void* b0, const void* b1, const void* b2, const void* b3, const void* b4,
                      u16* __restrict__ Wp, float* __restrict__ bp,
                      const void* __restrict__ x, const void* __restrict__ nonlab,
                      int* __restrict__ flags, float* __restrict__ accum){
  __shared__ int s_bad, s_ni, s_nf, s_nb;
  int t = threadIdx.x;
  if (t == 0){ s_bad = 0; s_ni = 0; s_nf = 0; s_nb = 0; }
  __syncthreads();
  // every block self-detects fm from x's first 1KB (L2-hot)
  {
    u32 w = ((const u32*)x)[t];
    u32 lo = w & 0xffffu, ex = (lo >> 7) & 0xffu;
    if (lo != 0u && (ex < 100u || ex > 140u)) atomicAdd(&s_bad, 1);
  }
  if (blockIdx.x == 0){
    if (t < 64){
      u32 v = ((const u32*)nonlab)[t];
      if (v > 1u) atomicAdd(&s_ni, 1);
      if (v != 0u && v != 0x3F800000u) atomicAdd(&s_nf, 1);
    }
    if (t < 128){
      u16 h = ((const u16*)nonlab)[t];
      if (h != 0 && h != 0x3F80) atomicAdd(&s_nb, 1);
    }
  }
  __syncthreads();
  int fm = (s_bad > 32) ? 1 : 0;
  if (blockIdx.x == 0){
    if (t == 0){
      flags[0] = fm;
      flags[1] = (s_ni == 0) ? 1 : ((s_nf == 0) ? 3 : ((s_nb == 0) ? 2 : 0));
    }
    for (int i = t; i < 1024; i += 256) accum[i] = 0.f;   // zeroes colsum + bcnt regions
  }
  int e = blockIdx.x * 256 + t;
  if (e < PW_TOT){
    const void* src; int off, DOUT;
    if      (e < PW_G2){ src = W0; off = PW_G1; DOUT = 128; }
    else if (e < PW_XY){ src = W1; off = PW_G2; DOUT = 32; }
    else if (e < PW_XH){ src = W2; off = PW_XY; DOUT = 128; }
    else if (e < PW_H2){ src = W3; off = PW_XH; DOUT = 128; }
    else if (e < PW_HY){ src = W4; off = PW_H2; DOUT = 192; }
    else               { src = W5; off = PW_HY; DOUT = 32; }
    int local = e - off;
    int k = local / DOUT, col = local - k * DOUT;
    u16 v = fm ? f2b(((const float*)src)[local]) : ((const u16*)src)[local];
    Wp[off + ((k >> 3) * DOUT + col) * 8 + (k & 7)] = v;
  }
  int eb = e - PW_TOT;
  if (eb >= 0 && eb < PB_TOT){
    float v = 0.f;
    if      (eb < 128) v = ldx(b0, eb, fm);
    else if (eb < 256) v = ldx(b1, eb - 128, fm);
    else if (eb < 384) v = ldx(b2, eb - 256, fm);
    else if (eb < 576) v = ldx(b3, eb - 384, fm);
    else if (eb < 704) v = 0.f;
    else               v = ldx(b4, eb - 704, fm);
    bp[eb] = v;
  }
}

// ---------------- bucketed scatter constants ----------------
#define BSH 9
#define NBK 196     // ceil(NN / 512)
#define CAP 16384   // per-bucket staging capacity (mean 8192 for uniform data, +91 sigma)

// ---------------- mega-kernel: xp = x@Wg1 (blocks 0..1562)  ||  binA (blocks 1563..1953) ----
__global__ __launch_bounds__(256) void k_front(const void* __restrict__ x,
     const u16* __restrict__ Wg1p, u16* __restrict__ xpo, const int* __restrict__ flags,
     const int* __restrict__ ei, const void* __restrict__ ew,
     int* __restrict__ bcnt, int2* __restrict__ stage){
  if (blockIdx.x < 1563){
    constexpr int STEPS = 4, CT = 4, RTW = 2, G = 2;
    int wid = blockIdx.x * 4 + (threadIdx.x >> 6);
    if (wid >= 6250) return;
    int g = wid % G; long chunk = wid / G;
    int lane = threadIdx.x & 63, n = lane & 15, q = lane >> 4;
    int colOff = g * 64;
    int fm = flags[0];
    short8 B[CT][STEPS];
    #pragma unroll
    for (int ct = 0; ct < CT; ++ct){
      int col = colOff + ct * 16 + n;
      #pragma unroll
      for (int s = 0; s < STEPS; ++s)
        B[ct][s] = *(const short8*)(Wg1p + (((s * 4 + q) * 128) + col) * 8);
    }
    for (int rt = 0; rt < RTW; ++rt){
      long rowbase = (chunk * RTW + rt) * 16;
      long arow = rowbase + n;
      v4f acc[CT] = {};
      #pragma unroll
      for (int s = 0; s < STEPS; ++s){
        short8 a;
        long base = arow * 128 + s * 32 + q * 8;
        if (fm){
          const float* xp = (const float*)x + base;
          float4 x0 = *(const float4*)xp, x1 = *(const float4*)(xp + 4);
          a[0] = (short)f2b(x0.x); a[1] = (short)f2b(x0.y);
          a[2] = (short)f2b(x0.z); a[3] = (short)f2b(x0.w);
          a[4] = (short)f2b(x1.x); a[5] = (short)f2b(x1.y);
          a[6] = (short)f2b(x1.z); a[7] = (short)f2b(x1.w);
        } else {
          a = *(const short8*)((const u16*)x + base);
        }
        #pragma unroll
        for (int ct = 0; ct < CT; ++ct)
          acc[ct] = __builtin_amdgcn_mfma_f32_16x16x32_bf16(a, B[ct][s], acc[ct], 0, 0, 0);
      }
      long orow = rowbase + q * 4;
      #pragma unroll
      for (int ct = 0; ct < CT; ++ct){
        int col = colOff + ct * 16 + n;
        #pragma unroll
        for (int r = 0; r < 4; ++r)
          xpo[(orow + r) * 128 + col] = f2b(acc[ct][r]);
      }
    }
  } else {
    __shared__ int lcnt[NBK];
    __shared__ int lbase[NBK];
    int t = threadIdx.x;
    int bid = blockIdx.x - 1563;
    for (int i = t; i < NBK; i += 256) lcnt[i] = 0;
    __syncthreads();
    int fm = flags[0];
    long e0 = (long)bid * 4096;
    int bb[16], ord[16], pk[16], wb[16];
    #pragma unroll
    for (int j = 0; j < 16; ++j){
      long e = e0 + j * 256 + t;
      bool v = e < EE;
      int r = v ? ei[e] : 0;
      int c = v ? ei[EE + e] : 0;
      float w = v ? ldx(ew, e, fm) : 0.f;
      int b = r >> BSH;
      bb[j] = v ? b : -1;
      pk[j] = ((r & 511) << 17) | c;   // rowInBucket (9b) | col (17b)
      wb[j] = __builtin_bit_cast(int, w);
      if (v) ord[j] = atomicAdd(&lcnt[b], 1);
    }
    __syncthreads();
    for (int i = t; i < NBK; i += 256){
      int c = lcnt[i];
      lbase[i] = c ? atomicAdd(&bcnt[i], c) : 0;
    }
    __syncthreads();
    #pragma unroll
    for (int j = 0; j < 16; ++j){
      if (bb[j] >= 0){
        int pos = lbase[bb[j]] + ord[j];
        if (pos < CAP) stage[(long)bb[j] * CAP + pos] = make_int2(pk[j], wb[j]);
      }
    }
  }
}

// per-bucket: self-computed prefix base, count rows, local scan -> rowptr, exact scatter
__global__ __launch_bounds__(512) void k_binB(const int* __restrict__ bcnt,
                      const int2* __restrict__ stage, int2* __restrict__ cpk,
                      int* __restrict__ rowptr){
  __shared__ int cnt[512];
  __shared__ int cur[512];
  __shared__ int sbase;
  int b = blockIdx.x, t = threadIdx.x;
  // bbase = sum bcnt[0..b-1] (bcnt L2-hot, 196 ints)
  cnt[t] = (t < b) ? bcnt[t] : 0;
  __syncthreads();
  for (int o = 256; o; o >>= 1){ if (t < o) cnt[t] += cnt[t + o]; __syncthreads(); }
  if (t == 0) sbase = cnt[0];
  __syncthreads();
  int bbase = sbase;
  if (b == 0 && t == 0) rowptr[NN] = EE;
  int r0 = b << BSH;
  int rows = min(512, NN - r0);
  cnt[t] = 0; __syncthreads();
  int cb = min(bcnt[b], CAP);
  const int2* sb = stage + (long)b * CAP;
  for (int j = t; j < cb; j += 512)
    atomicAdd(&cnt[((u32)sb[j].x) >> 17], 1);
  __syncthreads();
  int v = cnt[t];
  cur[t] = v; __syncthreads();
  for (int o = 1; o < 512; o <<= 1){
    int x = (t >= o) ? cur[t - o] : 0; __syncthreads();
    cur[t] += x; __syncthreads();
  }
  int excl = bbase + cur[t] - v;
  if (t < rows) rowptr[r0 + t] = excl;
  __syncthreads();
  cur[t] = excl;
  __syncthreads();
  for (int j = t; j < cb; j += 512){
    int2 w = sb[j];
    int rib = ((u32)w.x) >> 17;
    int pos = atomicAdd(&cur[rib], 1);
    cpk[pos] = make_int2(w.x & 0x1FFFF, w.y);
  }
}

// ---------------- SpMM D=128: one wave per row, paired-edge gather ----------------
// lanes 0-31 gather even edges, 32-63 odd edges, 8 B/lane (one dwordx2 moves 2 edges' rows).
// AG: agg[row] = sum_e w_e * agt[col_e]; EPI: out = relu(acc + bias)
template<bool AG, bool EPI>
__global__ __launch_bounds__(256) void k_spmm(const u16* __restrict__ in, u16* __restrict__ out,
                       const int* __restrict__ rowptr, const int2* __restrict__ cpk,
                       const float* __restrict__ agt, float* __restrict__ agg,
                       const float* __restrict__ bias){
  int wid  = blockIdx.x * 4 + (threadIdx.x >> 6);
  int lane = threadIdx.x & 63;
  if (wid >= NN) return;
  int half = lane >> 5, l16 = lane & 31;
  int s = rowptr[wid], e = rowptr[wid + 1];
  float a0 = 0.f, a1 = 0.f, a2 = 0.f, a3 = 0.f, aga = 0.f;
  for (int j = s; j < e; j += 8){
    int2 pe[4];
    if (j + 8 <= e){
      #pragma unroll
      for (int k = 0; k < 4; ++k) pe[k] = cpk[j + 2 * k + half];
    } else {
      #pragma unroll
      for (int k = 0; k < 4; ++k){
        int idx = j + 2 * k + half;
        int2 w = cpk[idx < e ? idx : j];
        if (idx >= e) w.y = 0;           // weight 0 -> fmaf no-op, bit-exact
        pe[k] = w;
      }
    }
    u32x2 u[4];
    #pragma unroll
    for (int k = 0; k < 4; ++k)
      u[k] = *(const u32x2*)(in + (long)pe[k].x * 128 + 4 * l16);
    if (AG && l16 == 0){
      #pragma unroll
      for (int k = 0; k < 4; ++k) aga = fmaf(i2f(pe[k].y), agt[pe[k].x], aga);
    }
    #pragma unroll
    for (int k = 0; k < 4; ++k){
      float wt = i2f(pe[k].y);
      a0 = fmaf(wt, lo2f(u[k].x), a0);
      a1 = fmaf(wt, hi2f(u[k].x), a1);
      a2 = fmaf(wt, lo2f(u[k].y), a2);
      a3 = fmaf(wt, hi2f(u[k].y), a3);
    }
  }
  a0 += __shfl_xor(a0, 32); a1 += __shfl_xor(a1, 32);
  a2 += __shfl_xor(a2, 32); a3 += __shfl_xor(a3, 32);
  if (AG) aga += __shfl_xor(aga, 32);
  if (EPI){
    a0 = fmaxf(a0 + bias[4 * l16],     0.f);
    a1 = fmaxf(a1 + bias[4 * l16 + 1], 0.f);
    a2 = fmaxf(a2 + bias[4 * l16 + 2], 0.f);
    a3 = fmaxf(a3 + bias[4 * l16 + 3], 0.f);
  }
  if (half == 0){
    u32x2 w;
    w.x = (u32)f2b(a0) | ((u32)f2b(a1) << 16);
    w.y = (u32)f2b(a2) | ((u32)f2b(a3) << 16);
    *(u32x2*)(out + (long)wid * 128 + 4 * l16) = w;
    if (AG && l16 == 0) agg[wid] = aga;
  }
}

// ---------------- SpMM D=32 bf16-table + f32 bias -> y_pred (paired-edge: 8 lanes x 8B) ----------------
__global__ __launch_bounds__(256) void k_spmm32b(const u16* __restrict__ in, void* __restrict__ out,
                       const int* __restrict__ rowptr, const int2* __restrict__ cpk,
                       const int* __restrict__ flags, const float* __restrict__ bp){
  int row = blockIdx.x * 16 + (threadIdx.x >> 4);
  int d = threadIdx.x & 15;
  if (row >= NN) return;
  int eh = d >> 3, d8 = d & 7;
  int fm = flags[0];
  int s = rowptr[row], e = rowptr[row + 1];
  float a0 = 0.f, a1 = 0.f, a2 = 0.f, a3 = 0.f;
  for (int j = s; j < e; j += 8){
    int2 p[4];
    if (j + 8 <= e){
      #pragma unroll
      for (int k = 0; k < 4; ++k) p[k] = cpk[j + 2 * k + eh];
    } else {
      #pragma unroll
      for (int k = 0; k < 4; ++k){
        int idx = j + 2 * k + eh;
        int2 w = cpk[idx < e ? idx : j];
        if (idx >= e) w.y = 0;
        p[k] = w;
      }
    }
    u32x2 u[4];
    #pragma unroll
    for (int k = 0; k < 4; ++k) u[k] = *(const u32x2*)(in + (long)p[k].x * 32 + 4 * d8);
    #pragma unroll
    for (int k = 0; k < 4; ++k){
      float wt = i2f(p[k].y);
      a0 = fmaf(wt, lo2f(u[k].x), a0);
      a1 = fmaf(wt, hi2f(u[k].x), a1);
      a2 = fmaf(wt, lo2f(u[k].y), a2);
      a3 = fmaf(wt, hi2f(u[k].y), a3);
    }
  }
  a0 += __shfl_xor(a0, 8); a1 += __shfl_xor(a1, 8);
  a2 += __shfl_xor(a2, 8); a3 += __shfl_xor(a3, 8);
  a0 += bp[4 * d8]; a1 += bp[4 * d8 + 1]; a2 += bp[4 * d8 + 2]; a3 += bp[4 * d8 + 3];
  if (eh == 0){
    if (fm){
      float4 w = make_float4(a0, a1, a2, a3);
      *(float4*)((float*)out + (long)row * 32 + 4 * d8) = w;
    } else {
      u32x2 w;
      w.x = (u32)f2b(a0) | ((u32)f2b(a1) << 16);
      w.y = (u32)f2b(a2) | ((u32)f2b(a3) << 16);
      *(u32x2*)((u16*)out + (long)row * 32 + 4 * d8) = w;
    }
  }
}

// ---------------- SpMM D=32 + gumbel/where -> y (paired-edge; skips labelled rows) ----------------
__global__ __launch_bounds__(256) void k_spmmg(const u16* __restrict__ in, u16* __restrict__ y,
                       const int* __restrict__ rowptr, const int2* __restrict__ cpk,
                       const int* __restrict__ flags, const void* __restrict__ bg2,
                       const void* __restrict__ ug, const void* __restrict__ ylab,
                       const void* __restrict__ nonlab){
  int row = blockIdx.x * 16 + (threadIdx.x >> 4);
  int d = threadIdx.x & 15;
  if (row >= NN) return;
  int fm = flags[0], mode = flags[1];
  bool nl;
  if      (mode == 1) nl = ((const int*)nonlab)[row] != 0;
  else if (mode == 3) nl = ((const float*)nonlab)[row] != 0.f;
  else if (mode == 2) nl = ((const u16*)nonlab)[row] != 0;
  else                nl = ((const unsigned char*)nonlab)[row] != 0;
  long base = (long)row * 32;
  if (!nl){
    u32 lo, hi;
    if (fm){
      lo = (u32)f2b(((const float*)ylab)[base + 2 * d]);
      hi = (u32)f2b(((const float*)ylab)[base + 2 * d + 1]);
    } else {
      lo = ((const u16*)ylab)[base + 2 * d];
      hi = ((const u16*)ylab)[base + 2 * d + 1];
    }
    *(u32*)(y + base + 2 * d) = lo | (hi << 16);
    return;
  }
  int eh = d >> 3, d8 = d & 7;
  int s = rowptr[row], e = rowptr[row + 1];
  float a0 = 0.f, a1 = 0.f, a2 = 0.f, a3 = 0.f;
  for (int j = s; j < e; j += 8){
    int2 p[4];
    if (j + 8 <= e){
      #pragma unroll
      for (int k = 0; k < 4; ++k) p[k] = cpk[j + 2 * k + eh];
    } else {
      #pragma unroll
      for (int k = 0; k < 4; ++k){
        int idx = j + 2 * k + eh;
        int2 w = cpk[idx < e ? idx : j];
        if (idx >= e) w.y = 0;
        p[k] = w;
      }
    }
    u32x2 u[4];
    #pragma unroll
    for (int k = 0; k < 4; ++k) u[k] = *(const u32x2*)(in + (long)p[k].x * 32 + 4 * d8);
    #pragma unroll
    for (int k = 0; k < 4; ++k){
      float wt = i2f(p[k].y);
      a0 = fmaf(wt, lo2f(u[k].x), a0);
      a1 = fmaf(wt, hi2f(u[k].x), a1);
      a2 = fmaf(wt, lo2f(u[k].y), a2);
      a3 = fmaf(wt, hi2f(u[k].y), a3);
    }
  }
  a0 += __shfl_xor(a0, 8); a1 += __shfl_xor(a1, 8);
  a2 += __shfl_xor(a2, 8); a3 += __shfl_xor(a3, 8);
  float av[4] = {a0, a1, a2, a3};
  int c0 = 4 * d8;
  float bm = -1e30f; int bi = 0;
  #pragma unroll
  for (int jj = 0; jj < 4; ++jj){
    float uu = ldx(ug, base + c0 + jj, fm);
    float g = -logf(-logf(uu + 1e-10f) + 1e-10f);
    float v = av[jj] + ldx(bg2, c0 + jj, fm) + g;
    if (v > bm){ bm = v; bi = c0 + jj; }    // strict > keeps first max
  }
  #pragma unroll
  for (int o = 1; o < 16; o <<= 1){
    float om = __shfl_xor(bm, o);
    int   oi = __shfl_xor(bi, o);
    if (om > bm || (om == bm && oi < bi)){ bm = om; bi = oi; }
  }
  if (eh == 0){
    u32x2 w;
    w.x = ((c0     == bi) ? 0x3F80u : 0u) | (((c0 + 1 == bi) ? 0x3F80u : 0u) << 16);
    w.y = ((c0 + 2 == bi) ? 0x3F80u : 0u) | (((c0 + 3 == bi) ? 0x3F80u : 0u) << 16);
    *(u32x2*)(y + base + c0) = w;
  }
}

// ---------------- generic MFMA GEMM (packed weights) ----------------
// AMODE 0: A[N,K]; 2: concat(A[N,128], A2[N,32])
// OMODE 0: bf16 out; 3: no store. CSUM: per-block column sums -> pb[blockIdx][128]
template<int K, int DOUT, int CT, int RTW, bool RELU, int AMODE, int OMODE, bool CSUM>
__global__ __launch_bounds__(256) void k_mm(const u16* __restrict__ A, const void* __restrict__ A2,
     const void* __restrict__ A3, const u16* __restrict__ Wp, const float* __restrict__ bp,
     void* __restrict__ outv, const int* __restrict__ flags, float* __restrict__ csacc){
  constexpr int STEPS = K / 32;
  constexpr int G = DOUT / (16 * CT);
  constexpr int CHUNKS = 6250 / RTW;      // N = 6250 * 16 exactly
  __shared__ float lsum[128];
  int wid = blockIdx.x * 4 + (threadIdx.x >> 6);
  if (wid >= G * CHUNKS) return;          // wave-uniform exit
  int g = wid % G; long chunk = wid / G;
  int lane = threadIdx.x & 63, n = lane & 15, q = lane >> 4;
  int colOff = g * CT * 16;

  if (CSUM){
    if (threadIdx.x < 128) lsum[threadIdx.x] = 0.f;
    __syncthreads();
  }

  short8 B[CT][STEPS];
  float bv[CT];
  #pragma unroll
  for (int ct = 0; ct < CT; ++ct){
    int col = colOff + ct * 16 + n;
    bv[ct] = bp[col];
    #pragma unroll
    for (int s = 0; s < STEPS; ++s)
      B[ct][s] = *(const short8*)(Wp + (((s * 4 + q) * DOUT) + col) * 8);
  }

  float csum[CT];
  #pragma unroll
  for (int ct = 0; ct < CT; ++ct) csum[ct] = 0.f;

  for (int rt = 0; rt < RTW; ++rt){
    long rowbase = (chunk * RTW + rt) * 16;
    long arow = rowbase + n;
    v4f acc[CT] = {};
    #pragma unroll
    for (int s = 0; s < STEPS; ++s){
      short8 a;
      if (AMODE == 0){
        a = *(const short8*)(A + arow * K + s * 32 + q * 8);
      } else { // AMODE==2: concat(hemb[N,128], y[N,32]), K=160
        if (s < 4) a = *(const short8*)(A + arow * 128 + s * 32 + q * 8);
        else       a = *(const short8*)((const u16*)A2 + arow * 32 + q * 8);
      }
      #pragma unroll
      for (int ct = 0; ct < CT; ++ct)
        acc[ct] = __builtin_amdgcn_mfma_f32_16x16x32_bf16(a, B[ct][s], acc[ct], 0, 0, 0);
    }
    long orow = rowbase + q * 4;
    #pragma unroll
    for (int ct = 0; ct < CT; ++ct){
      int col = colOff + ct * 16 + n;
      #pragma unroll
      for (int r = 0; r < 4; ++r){
        float v = acc[ct][r] + bv[ct];
        if (RELU) v = fmaxf(v, 0.f);
        if (CSUM) csum[ct] += v;
        if (OMODE != 3){
          long oi = (orow + r) * (long)DOUT + col;
          ((u16*)outv)[oi] = f2b(v);
        }
      }
    }
  }
  if (CSUM){
    #pragma unroll
    for (int ct = 0; ct < CT; ++ct){
      csum[ct] += __shfl_xor(csum[ct], 16);
      csum[ct] += __shfl_xor(csum[ct], 32);
      if (lane < 16) atomicAdd(&lsum[colOff + ct * 16 + n], csum[ct]);
    }
    __syncthreads();
    if (threadIdx.x < 128) csacc[(long)blockIdx.x * 128 + threadIdx.x] = lsum[threadIdx.x];
  }
}

// ---------------- fused h2 GEMM + (h2 @ Why) via LDS: never materializes h2 ----------------
__global__ __launch_bounds__(256) void k_mmh2(const u16* __restrict__ A, const float* __restrict__ AG2,
     const float* __restrict__ zbuf, const u16* __restrict__ Wh2p, const float* __restrict__ bh2p,
     const u16* __restrict__ Whyp, u16* __restrict__ tbuf){
  __shared__ u16 hl[16][200];   // 16x192 bf16 tile, row stride 200 (400B) to break bank conflicts
  int w = threadIdx.x >> 6;
  int lane = threadIdx.x & 63, n = lane & 15, q = lane >> 4;
  int colOff = w * 48;          // 4 waves x CT=3 x 16 = 192 cols

  short8 B[3][6];
  float bv[3];
  #pragma unroll
  for (int ct = 0; ct < 3; ++ct){
    int col = colOff + ct * 16 + n;
    bv[ct] = bh2p[col];
    #pragma unroll
    for (int s = 0; s < 6; ++s)
      B[ct][s] = *(const short8*)(Wh2p + (((s * 4 + q) * 192) + col) * 8);
  }
  short8 B2[2][6];
  if (w == 0){
    #pragma unroll
    for (int ct = 0; ct < 2; ++ct){
      int col = ct * 16 + n;
      #pragma unroll
      for (int s = 0; s < 6; ++s)
        B2[ct][s] = *(const short8*)(Whyp + (((s * 4 + q) * 32) + col) * 8);
    }
  }

  for (int rt = 0; rt < 2; ++rt){
    long rowbase = ((long)blockIdx.x * 2 + rt) * 16;
    long arow = rowbase + n;
    float agr = AG2[arow];
    v4f acc[3] = {};
    #pragma unroll
    for (int s = 0; s < 6; ++s){
      short8 a;
      if (s < 4) a = *(const short8*)(A + arow * 128 + s * 32 + q * 8);
      else {
        #pragma unroll
        for (int j = 0; j < 8; ++j) a[j] = (short)f2b(agr * zbuf[(s - 4) * 32 + q * 8 + j]);
      }
      #pragma unroll
      for (int ct = 0; ct < 3; ++ct)
        acc[ct] = __builtin_amdgcn_mfma_f32_16x16x32_bf16(a, B[ct][s], acc[ct], 0, 0, 0);
    }
    #pragma unroll
    for (int ct = 0; ct < 3; ++ct){
      int col = colOff + ct * 16 + n;
      #pragma unroll
      for (int r = 0; r < 4; ++r)
        hl[q * 4 + r][col] = f2b(fmaxf(acc[ct][r] + bv[ct], 0.f));
    }
    __syncthreads();
    if (w == 0){
      v4f a2[2] = {};
      #pragma unroll
      for (int s = 0; s < 6; ++s){
        short8 a = *(const short8*)(&hl[n][s * 32 + q * 8]);
        #pragma unroll
        for (int ct = 0; ct < 2; ++ct)
          a2[ct] = __builtin_amdgcn_mfma_f32_16x16x32_bf16(a, B2[ct][s], a2[ct], 0, 0, 0);
      }
      #pragma unroll
      for (int ct = 0; ct < 2; ++ct){
        int col = ct * 16 + n;
        #pragma unroll
        for (int r = 0; r < 4; ++r)
          tbuf[(rowbase + q * 4 + r) * 32 + col] = f2b(a2[ct][r]);
      }
    }
    __syncthreads();
  }
}

// ---------------- reduce per-block colsum partials: pb[1563][128] -> accum[128] ----------------
__global__ __launch_bounds__(256) void k_csred(const float* __restrict__ pb, float* __restrict__ accum){
  __shared__ float l[256];
  int c = blockIdx.x, t = threadIdx.x;
  float s = 0.f;
  for (int r = t; r < 1563; r += 256) s += pb[(long)r * 128 + c];
  l[t] = s; __syncthreads();
  for (int o = 128; o; o >>= 1){ if (t < o) l[t] += l[t + o]; __syncthreads(); }
  if (t == 0) accum[c] = l[0];
}

// ---------------- fused (x*dm)@Wxh -> relu -> row-normalize with z -> Hs, AG1 ----------------
__global__ __launch_bounds__(256) void k_mmnorm(const void* __restrict__ A2, const void* __restrict__ A3,
     const u16* __restrict__ Wp, const float* __restrict__ bp,
     u16* __restrict__ outHs, float* __restrict__ ag,
     const float* __restrict__ zbuf, const int* __restrict__ flags){
  constexpr int STEPS = 4, CT = 8, CHUNKS = 6250;   // RTW=1
  int wid = blockIdx.x * 4 + (threadIdx.x >> 6);
  if (wid >= CHUNKS) return;
  long chunk = wid;
  int lane = threadIdx.x & 63, n = lane & 15, q = lane >> 4;
  int fm = flags[0];

  short8 B[CT][STEPS];
  float bv[CT];
  #pragma unroll
  for (int ct = 0; ct < CT; ++ct){
    int col = ct * 16 + n;
    bv[ct] = bp[col];
    #pragma unroll
    for (int s = 0; s < STEPS; ++s)
      B[ct][s] = *(const short8*)(Wp + (((s * 4 + q) * 128) + col) * 8);
  }
  float zz = zbuf[64];

  {
    long rowbase = chunk * 16;
    long arow = rowbase + n;
    v4f acc[CT] = {};
    #pragma unroll
    for (int s = 0; s < STEPS; ++s){
      short8 a;
      long base = arow * 128 + s * 32 + q * 8;
      if (fm){
        const float* xp = (const float*)A2 + base;
        const float* dp = (const float*)A3 + base;
        float4 x0 = *(const float4*)xp, x1 = *(const float4*)(xp + 4);
        float4 d0 = *(const float4*)dp, d1 = *(const float4*)(dp + 4);
        a[0] = (short)f2b(x0.x * d0.x); a[1] = (short)f2b(x0.y * d0.y);
        a[2] = (short)f2b(x0.z * d0.z); a[3] = (short)f2b(x0.w * d0.w);
        a[4] = (short)f2b(x1.x * d1.x); a[5] = (short)f2b(x1.y * d1.y);
        a[6] = (short)f2b(x1.z * d1.z); a[7] = (short)f2b(x1.w * d1.w);
      } else {
        short8 xv = *(const short8*)((const u16*)A2 + base);
        short8 dv = *(const short8*)((const u16*)A3 + base);
        #pragma unroll
        for (int j = 0; j < 8; ++j) a[j] = (short)f2b(b2f((u16)xv[j]) * b2f((u16)dv[j]));
      }
      #pragma unroll
      for (int ct = 0; ct < CT; ++ct)
        acc[ct] = __builtin_amdgcn_mfma_f32_16x16x32_bf16(a, B[ct][s], acc[ct], 0, 0, 0);
    }
    // relu + row-norm epilogue
    float v[CT][4];
    float sqr[4] = {0.f, 0.f, 0.f, 0.f};
    #pragma unroll
    for (int ct = 0; ct < CT; ++ct){
      #pragma unroll
      for (int r = 0; r < 4; ++r){
        float t = fmaxf(acc[ct][r] + bv[ct], 0.f);
        v[ct][r] = t;
        sqr[r] += t * t;
      }
    }
    #pragma unroll
    for (int r = 0; r < 4; ++r){
      #pragma unroll
      for (int o = 1; o < 16; o <<= 1) sqr[r] += __shfl_xor(sqr[r], o);
    }
    float scale[4];
    #pragma unroll
    for (int r = 0; r < 4; ++r) scale[r] = 1.f / (sqrtf(sqr[r] + zz) + 1e-6f);
    long orow = rowbase + q * 4;
    #pragma unroll
    for (int ct = 0; ct < CT; ++ct){
      int col = ct * 16 + n;
      #pragma unroll
      for (int r = 0; r < 4; ++r)
        outHs[(orow + r) * 128 + col] = f2b(v[ct][r] * scale[r]);
    }
    if (n == 0){
      #pragma unroll
      for (int r = 0; r < 4; ++r) ag[orow + r] = scale[r];
    }
  }
}

// ---------------- tiny tail: r_graph -> hr -> mu/sigma -> z, plus ||z||^2 ----------------
__global__ void k_z(const float* __restrict__ accum,
                    const void* Whr, const void* bhr, const void* Wrh, const void* brh,
                    const void* Wmu, const void* bmu, const void* Wsig, const void* bsig,
                    const void* zeps, float* __restrict__ zout, const int* __restrict__ flags){
  __shared__ float hm[128], rg[128], hr[128], zl[64];
  int t = threadIdx.x, fm = flags[0];
  hm[t] = accum[t] * (1.0f / 100000.0f);
  __syncthreads();
  { float s = ldx(bhr, t, fm);
    for (int k = 0; k < 128; ++k) s = fmaf(hm[k], ldx(Whr, (long)k * 128 + t, fm), s);
    rg[t] = s; }
  __syncthreads();
  { float s = ldx(brh, t, fm);
    for (int k = 0; k < 128; ++k) s = fmaf(rg[k], ldx(Wrh, (long)k * 128 + t, fm), s);
    hr[t] = fmaxf(s, 0.f); }
  __syncthreads();
  if (t < 64){
    float m = ldx(bmu, t, fm), sv = ldx(bsig, t, fm);
    for (int k = 0; k < 128; ++k){
      float h = hr[k];
      m  = fmaf(h, ldx(Wmu,  (long)k * 64 + t, fm), m);
      sv = fmaf(h, ldx(Wsig, (long)k * 64 + t, fm), sv);
    }
    float sig = 0.1f + 0.9f / (1.f + expf(-sv));
    float z = fmaf(sig, ldx(zeps, t, fm), m);
    zl[t] = z; zout[t] = z;
  }
  __syncthreads();
  if (t == 0){ float ss = 0.f; for (int j = 0; j < 64; ++j) ss += zl[j] * zl[j]; zout[64] = ss; }
}

extern "C" void kernel_launch(void* const* d_in, const int* in_sizes, int n_in,
                              void* d_out, int out_size, void* d_ws, size_t ws_size,
                              hipStream_t stream){
  const void* x    = d_in[0];
  const void* ylab = d_in[1];
  const int*  ei   = (const int*)d_in[2];
  const void* ew   = d_in[3];
  const void* nonlab = d_in[4];
  const void* dm   = d_in[5];
  const void* ug   = d_in[6];
  const void* zeps = d_in[7];
  const void* Wg1 = d_in[8],  *bg1 = d_in[9];
  const void* Wg2 = d_in[10], *bg2 = d_in[11];
  const void* Wxy = d_in[12], *bxy = d_in[13];
  const void* Whr = d_in[14], *bhr = d_in[15];
  const void* Wrh = d_in[16], *brh = d_in[17];
  const void* Wmu = d_in[18], *bmu = d_in[19];
  const void* Wsg = d_in[20], *bsg = d_in[21];
  const void* Wxh = d_in[22], *bxh = d_in[23];
  const void* Wh2 = d_in[24], *bh2 = d_in[25];
  const void* Why = d_in[26], *bhy = d_in[27];

  char* ws = (char*)d_ws;
  size_t off = 0;
  auto alloc = [&](size_t bytes){ void* p = ws + off; off += (bytes + 511) & ~(size_t)511; return p; };
  int*   flags  = (int*)  alloc(256);
  int*   rowptr = (int*)  alloc((size_t)(NN + 1) * 4);
  float* accum  = (float*)alloc(1024 * 4);   // [0:128) colsum, [128:192) z, [192] ||z||^2, [512:708) bcnt
  u16*   Wpack  = (u16*)  alloc((size_t)PW_TOT * 2);
  float* bpack  = (float*)alloc((size_t)PB_TOT * 4);
  float* AG1    = (float*)alloc((size_t)NN * 4);   // per-row norm scale
  float* AG2    = (float*)alloc((size_t)NN * 4);   // spmm of scale
  float* pb     = (float*)alloc((size_t)1563 * 128 * 4);  // per-block colsum partials
  int2*  cpk    = (int2*) alloc((size_t)EE * 8);
  u16*   B0     = (u16*)  alloc((size_t)NN * 192 * 2);
  u16*   B1     = (u16*)  alloc((size_t)NN * 192 * 2);
  // layout: stage=B0 (dead after binB); xp=B1[0:128] (dead after S1); h_emb=B0[0:128];
  // yproj=B0[128:160); ybuf=B1[160:192); Hs=B1[0:128]; tbuf(bf16)=B1[0:32) (B0 live as spmmH!)
  u16* yproj = B0 + (size_t)NN * 128;   // [N,32] bf16 (h_emb @ Wg2)
  u16* ybuf  = B1 + (size_t)NN * 160;   // [N,32] bf16 (y)
  int2* stage = (int2*)B0;
  u16* tbuf = B1;                       // [N,32] bf16 (h2 @ Why) -- B1 free after S3 consumed Hs
  int* bcnt = (int*)(accum + 512);      // NBK per-bucket staged counts (zeroed by k_pack)

  // pack (+detect +accum zero) -- must precede everything that reads flags/bcnt/Wpack
  k_pack<<<(PW_TOT + PB_TOT + 255) / 256, 256, 0, stream>>>(Wg1, Wg2, Wxy, Wxh, Wh2, Why,
                                                            bg1, bxy, bxh, bh2, bhy, Wpack, bpack,
                                                            x, nonlab, flags, accum);
  // mega-kernel: xp GEMM (1563 blocks) overlapped with binA (391 blocks)
  k_front<<<1954, 256, 0, stream>>>(x, Wpack + PW_G1, B1, flags, ei, ew, bcnt, stage);
  k_binB <<<NBK, 512, 0, stream>>>(bcnt, stage, cpk, rowptr);   // scanB folded in (self prefix)
  // pipeline
  k_spmm<false,true ><<<25000, 256, 0, stream>>>(B1, B0, rowptr, cpk, nullptr, nullptr, bpack + PB_G1); // S1: h_emb -> B0
  k_mm<128,32 ,2,1,false,0,0,false><<<1563, 256, 0, stream>>>(B0, nullptr, nullptr, Wpack + PW_G2, bpack + PB_ZERO, yproj, flags, nullptr); // yproj = h_emb@Wg2
  k_spmmg<<<6250, 256, 0, stream>>>(yproj, ybuf, rowptr, cpk, flags, bg2, ug, ylab, nonlab);     // S2'+gumbel -> y
  k_mm<160,128,4,2,true ,2,3,true ><<<1563, 256, 0, stream>>>(B0, ybuf, nullptr, Wpack + PW_XY, bpack + PB_XY, nullptr, flags, pb); // colsum partials
  k_csred<<<128, 256, 0, stream>>>(pb, accum);                                                   // reduce -> accum[0:128)
  k_z<<<1, 128, 0, stream>>>(accum, Whr, bhr, Wrh, brh, Wmu, bmu, Wsg, bsg, zeps, accum + 128, flags);
  k_mmnorm<<<1563, 256, 0, stream>>>(x, dm, Wpack + PW_XH, bpack + PB_XH, B1, AG1, accum + 128, flags); // Hs->B1, AG1
  k_spmm<true ,false><<<25000, 256, 0, stream>>>(B1, B0, rowptr, cpk, AG1, AG2, nullptr);        // S3: Hs->B0, agg->AG2
  k_mmh2<<<3125, 256, 0, stream>>>(B0, AG2, accum + 128, Wpack + PW_H2, bpack + PB_H2,
                                   Wpack + PW_HY, tbuf);                                         // fused h2+Why -> tbuf (B1)
  k_spmm32b<<<6250, 256, 0, stream>>>(tbuf, d_out, rowptr, cpk, flags, bpack + PB_HY);           // S4': y_pred
}

// Round 14
// 563.975 us; speedup vs baseline: 1.0241x; 1.0072x over previous
//
#include <hip/hip_runtime.h>
#include <hip/hip_bf16.h>

#define NN 100000
#define EE 1600000

typedef unsigned short u16;
typedef unsigned int   u32;
typedef short short8 __attribute__((ext_vector_type(8)));
typedef float v4f    __attribute__((ext_vector_type(4)));
typedef u32 u32x2    __attribute__((ext_vector_type(2)));
typedef u32 u32x4    __attribute__((ext_vector_type(4)));

__device__ __forceinline__ float b2f(u16 h){ u32 u = ((u32)h) << 16; return __builtin_bit_cast(float, u); }
__device__ __forceinline__ float lo2f(u32 u){ return __builtin_bit_cast(float, u << 16); }
__device__ __forceinline__ float hi2f(u32 u){ return __builtin_bit_cast(float, u & 0xffff0000u); }
__device__ __forceinline__ u16   f2b(float f){ __hip_bfloat16 h = __float2bfloat16(f); return __builtin_bit_cast(u16, h); }
__device__ __forceinline__ float ldx(const void* p, long i, int fm){
  return fm ? ((const float*)p)[i] : b2f(((const u16*)p)[i]);
}
__device__ __forceinline__ float i2f(int v){ return __builtin_bit_cast(float, v); }

// ---------------- weight packing + dtype detect + accum zero (fused) ----------------
// Wp[off + ((k>>3)*DOUT + col)*8 + (k&7)] = W[k*DOUT + col]
#define PW_G1 0        // Wg1 128x128
#define PW_G2 16384    // Wg2 128x32
#define PW_XY 20480    // Wxy 160x128
#define PW_XH 40960    // Wxh 128x128
#define PW_H2 57344    // Wh2 192x192
#define PW_HY 94208    // Why 192x32
#define PW_TOT 100352
#define PB_G1 0
#define PB_XY 128
#define PB_XH 256
#define PB_H2 384
#define PB_ZERO 576
#define PB_HY 704
#define PB_TOT 736

__global__ __launch_bounds__(256) void k_pack(const void* W0, const void* W1, const void* W2,
                      const void* W3, const void* W4, const void* W5,
                      const void* b0, const void* b1, const void* b2, const void* b3, const void* b4,
                      u16* __restrict__ Wp, float* __restrict__ bp,
                      const void* __restrict__ x, const void* __restrict__ nonlab,
                      int* __restrict__ flags, float* __restrict__ accum){
  __shared__ int s_bad, s_ni, s_nf, s_nb;
  int t = threadIdx.x;
  if (t == 0){ s_bad = 0; s_ni = 0; s_nf = 0; s_nb = 0; }
  __syncthreads();
  // every block self-detects fm from x's first 1KB (L2-hot)
  {
    u32 w = ((const u32*)x)[t];
    u32 lo = w & 0xffffu, ex = (lo >> 7) & 0xffu;
    if (lo != 0u && (ex < 100u || ex > 140u)) atomicAdd(&s_bad, 1);
  }
  if (blockIdx.x == 0){
    if (t < 64){
      u32 v = ((const u32*)nonlab)[t];
      if (v > 1u) atomicAdd(&s_ni, 1);
      if (v != 0u && v != 0x3F800000u) atomicAdd(&s_nf, 1);
    }
    if (t < 128){
      u16 h = ((const u16*)nonlab)[t];
      if (h != 0 && h != 0x3F80) atomicAdd(&s_nb, 1);
    }
  }
  __syncthreads();
  int fm = (s_bad > 32) ? 1 : 0;
  if (blockIdx.x == 0){
    if (t == 0){
      flags[0] = fm;
      flags[1] = (s_ni == 0) ? 1 : ((s_nf == 0) ? 3 : ((s_nb == 0) ? 2 : 0));
    }
    for (int i = t; i < 1024; i += 256) accum[i] = 0.f;   // zeroes colsum + bcnt regions
  }
  int e = blockIdx.x * 256 + t;
  if (e < PW_TOT){
    const void* src; int off, DOUT;
    if      (e < PW_G2){ src = W0; off = PW_G1; DOUT = 128; }
    else if (e < PW_XY){ src = W1; off = PW_G2; DOUT = 32; }
    else if (e < PW_XH){ src = W2; off = PW_XY; DOUT = 128; }
    else if (e < PW_H2){ src = W3; off = PW_XH; DOUT = 128; }
    else if (e < PW_HY){ src = W4; off = PW_H2; DOUT = 192; }
    else               { src = W5; off = PW_HY; DOUT = 32; }
    int local = e - off;
    int k = local / DOUT, col = local - k * DOUT;
    u16 v = fm ? f2b(((const float*)src)[local]) : ((const u16*)src)[local];
    Wp[off + ((k >> 3) * DOUT + col) * 8 + (k & 7)] = v;
  }
  int eb = e - PW_TOT;
  if (eb >= 0 && eb < PB_TOT){
    float v = 0.f;
    if      (eb < 128) v = ldx(b0, eb, fm);
    else if (eb < 256) v = ldx(b1, eb - 128, fm);
    else if (eb < 384) v = ldx(b2, eb - 256, fm);
    else if (eb < 576) v = ldx(b3, eb - 384, fm);
    else if (eb < 704) v = 0.f;
    else               v = ldx(b4, eb - 704, fm);
    bp[eb] = v;
  }
}

// ---------------- bucketed scatter constants ----------------
#define BSH 9
#define NBK 196     // ceil(NN / 512)
#define CAP 16384   // per-bucket staging capacity (mean 8192 for uniform data, +91 sigma)

// ---------------- mega-kernel: xp = x@Wg1 (blocks 0..1562)  ||  binA (blocks 1563..1953) ----
__global__ __launch_bounds__(256) void k_front(const void* __restrict__ x,
     const u16* __restrict__ Wg1p, u16* __restrict__ xpo, const int* __restrict__ flags,
     const int* __restrict__ ei, const void* __restrict__ ew,
     int* __restrict__ bcnt, int2* __restrict__ stage){
  if (blockIdx.x < 1563){
    constexpr int STEPS = 4, CT = 4, RTW = 2, G = 2;
    int wid = blockIdx.x * 4 + (threadIdx.x >> 6);
    if (wid >= 6250) return;
    int g = wid % G; long chunk = wid / G;
    int lane = threadIdx.x & 63, n = lane & 15, q = lane >> 4;
    int colOff = g * 64;
    int fm = flags[0];
    short8 B[CT][STEPS];
    #pragma unroll
    for (int ct = 0; ct < CT; ++ct){
      int col = colOff + ct * 16 + n;
      #pragma unroll
      for (int s = 0; s < STEPS; ++s)
        B[ct][s] = *(const short8*)(Wg1p + (((s * 4 + q) * 128) + col) * 8);
    }
    for (int rt = 0; rt < RTW; ++rt){
      long rowbase = (chunk * RTW + rt) * 16;
      long arow = rowbase + n;
      v4f acc[CT] = {};
      #pragma unroll
      for (int s = 0; s < STEPS; ++s){
        short8 a;
        long base = arow * 128 + s * 32 + q * 8;
        if (fm){
          const float* xp = (const float*)x + base;
          float4 x0 = *(const float4*)xp, x1 = *(const float4*)(xp + 4);
          a[0] = (short)f2b(x0.x); a[1] = (short)f2b(x0.y);
          a[2] = (short)f2b(x0.z); a[3] = (short)f2b(x0.w);
          a[4] = (short)f2b(x1.x); a[5] = (short)f2b(x1.y);
          a[6] = (short)f2b(x1.z); a[7] = (short)f2b(x1.w);
        } else {
          a = *(const short8*)((const u16*)x + base);
        }
        #pragma unroll
        for (int ct = 0; ct < CT; ++ct)
          acc[ct] = __builtin_amdgcn_mfma_f32_16x16x32_bf16(a, B[ct][s], acc[ct], 0, 0, 0);
      }
      long orow = rowbase + q * 4;
      #pragma unroll
      for (int ct = 0; ct < CT; ++ct){
        int col = colOff + ct * 16 + n;
        #pragma unroll
        for (int r = 0; r < 4; ++r)
          xpo[(orow + r) * 128 + col] = f2b(acc[ct][r]);
      }
    }
  } else {
    __shared__ int lcnt[NBK];
    __shared__ int lbase[NBK];
    int t = threadIdx.x;
    int bid = blockIdx.x - 1563;
    for (int i = t; i < NBK; i += 256) lcnt[i] = 0;
    __syncthreads();
    int fm = flags[0];
    long e0 = (long)bid * 4096;
    int bb[16], ord[16], pk[16], wb[16];
    #pragma unroll
    for (int j = 0; j < 16; ++j){
      long e = e0 + j * 256 + t;
      bool v = e < EE;
      int r = v ? ei[e] : 0;
      int c = v ? ei[EE + e] : 0;
      float w = v ? ldx(ew, e, fm) : 0.f;
      int b = r >> BSH;
      bb[j] = v ? b : -1;
      pk[j] = ((r & 511) << 17) | c;   // rowInBucket (9b) | col (17b)
      wb[j] = __builtin_bit_cast(int, w);
      if (v) ord[j] = atomicAdd(&lcnt[b], 1);
    }
    __syncthreads();
    for (int i = t; i < NBK; i += 256){
      int c = lcnt[i];
      lbase[i] = c ? atomicAdd(&bcnt[i], c) : 0;
    }
    __syncthreads();
    #pragma unroll
    for (int j = 0; j < 16; ++j){
      if (bb[j] >= 0){
        int pos = lbase[bb[j]] + ord[j];
        if (pos < CAP) stage[(long)bb[j] * CAP + pos] = make_int2(pk[j], wb[j]);
      }
    }
  }
}

// per-bucket: self-computed prefix base, count rows, local scan -> rowptr, exact scatter
__global__ __launch_bounds__(512) void k_binB(const int* __restrict__ bcnt,
                      const int2* __restrict__ stage, int2* __restrict__ cpk,
                      int* __restrict__ rowptr){
  __shared__ int cnt[512];
  __shared__ int cur[512];
  __shared__ int sbase;
  int b = blockIdx.x, t = threadIdx.x;
  // bbase = sum bcnt[0..b-1] (bcnt L2-hot, 196 ints)
  cnt[t] = (t < b) ? bcnt[t] : 0;
  __syncthreads();
  for (int o = 256; o; o >>= 1){ if (t < o) cnt[t] += cnt[t + o]; __syncthreads(); }
  if (t == 0) sbase = cnt[0];
  __syncthreads();
  int bbase = sbase;
  if (b == 0 && t == 0) rowptr[NN] = EE;
  int r0 = b << BSH;
  int rows = min(512, NN - r0);
  cnt[t] = 0; __syncthreads();
  int cb = min(bcnt[b], CAP);
  const int2* sb = stage + (long)b * CAP;
  for (int j = t; j < cb; j += 512)
    atomicAdd(&cnt[((u32)sb[j].x) >> 17], 1);
  __syncthreads();
  int v = cnt[t];
  cur[t] = v; __syncthreads();
  for (int o = 1; o < 512; o <<= 1){
    int x = (t >= o) ? cur[t - o] : 0; __syncthreads();
    cur[t] += x; __syncthreads();
  }
  int excl = bbase + cur[t] - v;
  if (t < rows) rowptr[r0 + t] = excl;
  __syncthreads();
  cur[t] = excl;
  __syncthreads();
  for (int j = t; j < cb; j += 512){
    int2 w = sb[j];
    int rib = ((u32)w.x) >> 17;
    int pos = atomicAdd(&cur[rib], 1);
    cpk[pos] = make_int2(w.x & 0x1FFFF, w.y);
  }
}

// ---------------- SpMM D=128: one wave per row, QUAD-edge gather ----------------
// 16 lanes per edge x 16B (dwordx4): one load instr moves 4 edges' rows (1KB).
// Per 8 edges: 2 cpk + 2 gather instrs (was 4+4). 8 accumulators/lane; shfl_xor(16/32) combine.
// AG: agg[row] = sum_e w_e * agt[col_e]; EPI: out = relu(acc + bias)
template<bool AG, bool EPI>
__global__ __launch_bounds__(256) void k_spmm(const u16* __restrict__ in, u16* __restrict__ out,
                       const int* __restrict__ rowptr, const int2* __restrict__ cpk,
                       const float* __restrict__ agt, float* __restrict__ agg,
                       const float* __restrict__ bias){
  int wid  = blockIdx.x * 4 + (threadIdx.x >> 6);
  int lane = threadIdx.x & 63;
  if (wid >= NN) return;
  int qt = lane >> 4, l8 = lane & 15;   // quarter, lane-in-quarter
  int s = rowptr[wid], e = rowptr[wid + 1];
  float a0 = 0.f, a1 = 0.f, a2 = 0.f, a3 = 0.f;
  float a4 = 0.f, a5 = 0.f, a6 = 0.f, a7 = 0.f;
  float aga = 0.f;
  for (int j = s; j < e; j += 8){
    int2 pe[2];
    if (j + 8 <= e){
      #pragma unroll
      for (int k = 0; k < 2; ++k) pe[k] = cpk[j + 4 * k + qt];
    } else {
      #pragma unroll
      for (int k = 0; k < 2; ++k){
        int idx = j + 4 * k + qt;
        int2 w = cpk[idx < e ? idx : j];
        if (idx >= e) w.y = 0;           // weight 0 -> fmaf no-op, bit-exact
        pe[k] = w;
      }
    }
    u32x4 u[2];
    #pragma unroll
    for (int k = 0; k < 2; ++k)
      u[k] = *(const u32x4*)(in + (long)pe[k].x * 128 + 8 * l8);
    if (AG && l8 == 0){
      #pragma unroll
      for (int k = 0; k < 2; ++k) aga = fmaf(i2f(pe[k].y), agt[pe[k].x], aga);
    }
    #pragma unroll
    for (int k = 0; k < 2; ++k){
      float wt = i2f(pe[k].y);
      a0 = fmaf(wt, lo2f(u[k].x), a0);
      a1 = fmaf(wt, hi2f(u[k].x), a1);
      a2 = fmaf(wt, lo2f(u[k].y), a2);
      a3 = fmaf(wt, hi2f(u[k].y), a3);
      a4 = fmaf(wt, lo2f(u[k].z), a4);
      a5 = fmaf(wt, hi2f(u[k].z), a5);
      a6 = fmaf(wt, lo2f(u[k].w), a6);
      a7 = fmaf(wt, hi2f(u[k].w), a7);
    }
  }
  // combine the 4 quarters
  a0 += __shfl_xor(a0, 16); a0 += __shfl_xor(a0, 32);
  a1 += __shfl_xor(a1, 16); a1 += __shfl_xor(a1, 32);
  a2 += __shfl_xor(a2, 16); a2 += __shfl_xor(a2, 32);
  a3 += __shfl_xor(a3, 16); a3 += __shfl_xor(a3, 32);
  a4 += __shfl_xor(a4, 16); a4 += __shfl_xor(a4, 32);
  a5 += __shfl_xor(a5, 16); a5 += __shfl_xor(a5, 32);
  a6 += __shfl_xor(a6, 16); a6 += __shfl_xor(a6, 32);
  a7 += __shfl_xor(a7, 16); a7 += __shfl_xor(a7, 32);
  if (AG){ aga += __shfl_xor(aga, 16); aga += __shfl_xor(aga, 32); }
  if (EPI){
    a0 = fmaxf(a0 + bias[8 * l8],     0.f);
    a1 = fmaxf(a1 + bias[8 * l8 + 1], 0.f);
    a2 = fmaxf(a2 + bias[8 * l8 + 2], 0.f);
    a3 = fmaxf(a3 + bias[8 * l8 + 3], 0.f);
    a4 = fmaxf(a4 + bias[8 * l8 + 4], 0.f);
    a5 = fmaxf(a5 + bias[8 * l8 + 5], 0.f);
    a6 = fmaxf(a6 + bias[8 * l8 + 6], 0.f);
    a7 = fmaxf(a7 + bias[8 * l8 + 7], 0.f);
  }
  if (qt == 0){
    u32x4 w;
    w.x = (u32)f2b(a0) | ((u32)f2b(a1) << 16);
    w.y = (u32)f2b(a2) | ((u32)f2b(a3) << 16);
    w.z = (u32)f2b(a4) | ((u32)f2b(a5) << 16);
    w.w = (u32)f2b(a6) | ((u32)f2b(a7) << 16);
    *(u32x4*)(out + (long)wid * 128 + 8 * l8) = w;
    if (AG && l8 == 0) agg[wid] = aga;
  }
}

// ---------------- SpMM D=32 bf16-table + f32 bias -> y_pred (QUAD-edge: 4 lanes x 16B) ----------------
__global__ __launch_bounds__(256) void k_spmm32b(const u16* __restrict__ in, void* __restrict__ out,
                       const int* __restrict__ rowptr, const int2* __restrict__ cpk,
                       const int* __restrict__ flags, const float* __restrict__ bp){
  int row = blockIdx.x * 16 + (threadIdx.x >> 4);
  int d = threadIdx.x & 15;
  if (row >= NN) return;
  int sub = d >> 2, l4 = d & 3;
  int fm = flags[0];
  int s = rowptr[row], e = rowptr[row + 1];
  float a0 = 0.f, a1 = 0.f, a2 = 0.f, a3 = 0.f;
  float a4 = 0.f, a5 = 0.f, a6 = 0.f, a7 = 0.f;
  for (int j = s; j < e; j += 8){
    int2 p[2];
    if (j + 8 <= e){
      #pragma unroll
      for (int k = 0; k < 2; ++k) p[k] = cpk[j + 4 * k + sub];
    } else {
      #pragma unroll
      for (int k = 0; k < 2; ++k){
        int idx = j + 4 * k + sub;
        int2 w = cpk[idx < e ? idx : j];
        if (idx >= e) w.y = 0;
        p[k] = w;
      }
    }
    u32x4 u[2];
    #pragma unroll
    for (int k = 0; k < 2; ++k) u[k] = *(const u32x4*)(in + (long)p[k].x * 32 + 8 * l4);
    #pragma unroll
    for (int k = 0; k < 2; ++k){
      float wt = i2f(p[k].y);
      a0 = fmaf(wt, lo2f(u[k].x), a0);
      a1 = fmaf(wt, hi2f(u[k].x), a1);
      a2 = fmaf(wt, lo2f(u[k].y), a2);
      a3 = fmaf(wt, hi2f(u[k].y), a3);
      a4 = fmaf(wt, lo2f(u[k].z), a4);
      a5 = fmaf(wt, hi2f(u[k].z), a5);
      a6 = fmaf(wt, lo2f(u[k].w), a6);
      a7 = fmaf(wt, hi2f(u[k].w), a7);
    }
  }
  a0 += __shfl_xor(a0, 4); a0 += __shfl_xor(a0, 8);
  a1 += __shfl_xor(a1, 4); a1 += __shfl_xor(a1, 8);
  a2 += __shfl_xor(a2, 4); a2 += __shfl_xor(a2, 8);
  a3 += __shfl_xor(a3, 4); a3 += __shfl_xor(a3, 8);
  a4 += __shfl_xor(a4, 4); a4 += __shfl_xor(a4, 8);
  a5 += __shfl_xor(a5, 4); a5 += __shfl_xor(a5, 8);
  a6 += __shfl_xor(a6, 4); a6 += __shfl_xor(a6, 8);
  a7 += __shfl_xor(a7, 4); a7 += __shfl_xor(a7, 8);
  a0 += bp[8 * l4];     a1 += bp[8 * l4 + 1]; a2 += bp[8 * l4 + 2]; a3 += bp[8 * l4 + 3];
  a4 += bp[8 * l4 + 4]; a5 += bp[8 * l4 + 5]; a6 += bp[8 * l4 + 6]; a7 += bp[8 * l4 + 7];
  if (sub == 0){
    if (fm){
      float* op = (float*)out + (long)row * 32 + 8 * l4;
      *(float4*)op       = make_float4(a0, a1, a2, a3);
      *(float4*)(op + 4) = make_float4(a4, a5, a6, a7);
    } else {
      u32x4 w;
      w.x = (u32)f2b(a0) | ((u32)f2b(a1) << 16);
      w.y = (u32)f2b(a2) | ((u32)f2b(a3) << 16);
      w.z = (u32)f2b(a4) | ((u32)f2b(a5) << 16);
      w.w = (u32)f2b(a6) | ((u32)f2b(a7) << 16);
      *(u32x4*)((u16*)out + (long)row * 32 + 8 * l4) = w;
    }
  }
}

// ---------------- SpMM D=32 + gumbel/where -> y (paired-edge; skips labelled rows) ----------------
__global__ __launch_bounds__(256) void k_spmmg(const u16* __restrict__ in, u16* __restrict__ y,
                       const int* __restrict__ rowptr, const int2* __restrict__ cpk,
                       const int* __restrict__ flags, const void* __restrict__ bg2,
                       const void* __restrict__ ug, const void* __restrict__ ylab,
                       const void* __restrict__ nonlab){
  int row = blockIdx.x * 16 + (threadIdx.x >> 4);
  int d = threadIdx.x & 15;
  if (row >= NN) return;
  int fm = flags[0], mode = flags[1];
  bool nl;
  if      (mode == 1) nl = ((const int*)nonlab)[row] != 0;
  else if (mode == 3) nl = ((const float*)nonlab)[row] != 0.f;
  else if (mode == 2) nl = ((const u16*)nonlab)[row] != 0;
  else                nl = ((const unsigned char*)nonlab)[row] != 0;
  long base = (long)row * 32;
  if (!nl){
    u32 lo, hi;
    if (fm){
      lo = (u32)f2b(((const float*)ylab)[base + 2 * d]);
      hi = (u32)f2b(((const float*)ylab)[base + 2 * d + 1]);
    } else {
      lo = ((const u16*)ylab)[base + 2 * d];
      hi = ((const u16*)ylab)[base + 2 * d + 1];
    }
    *(u32*)(y + base + 2 * d) = lo | (hi << 16);
    return;
  }
  int eh = d >> 3, d8 = d & 7;
  int s = rowptr[row], e = rowptr[row + 1];
  float a0 = 0.f, a1 = 0.f, a2 = 0.f, a3 = 0.f;
  for (int j = s; j < e; j += 8){
    int2 p[4];
    if (j + 8 <= e){
      #pragma unroll
      for (int k = 0; k < 4; ++k) p[k] = cpk[j + 2 * k + eh];
    } else {
      #pragma unroll
      for (int k = 0; k < 4; ++k){
        int idx = j + 2 * k + eh;
        int2 w = cpk[idx < e ? idx : j];
        if (idx >= e) w.y = 0;
        p[k] = w;
      }
    }
    u32x2 u[4];
    #pragma unroll
    for (int k = 0; k < 4; ++k) u[k] = *(const u32x2*)(in + (long)p[k].x * 32 + 4 * d8);
    #pragma unroll
    for (int k = 0; k < 4; ++k){
      float wt = i2f(p[k].y);
      a0 = fmaf(wt, lo2f(u[k].x), a0);
      a1 = fmaf(wt, hi2f(u[k].x), a1);
      a2 = fmaf(wt, lo2f(u[k].y), a2);
      a3 = fmaf(wt, hi2f(u[k].y), a3);
    }
  }
  a0 += __shfl_xor(a0, 8); a1 += __shfl_xor(a1, 8);
  a2 += __shfl_xor(a2, 8); a3 += __shfl_xor(a3, 8);
  float av[4] = {a0, a1, a2, a3};
  int c0 = 4 * d8;
  float bm = -1e30f; int bi = 0;
  #pragma unroll
  for (int jj = 0; jj < 4; ++jj){
    float uu = ldx(ug, base + c0 + jj, fm);
    float g = -logf(-logf(uu + 1e-10f) + 1e-10f);
    float v = av[jj] + ldx(bg2, c0 + jj, fm) + g;
    if (v > bm){ bm = v; bi = c0 + jj; }    // strict > keeps first max
  }
  #pragma unroll
  for (int o = 1; o < 16; o <<= 1){
    float om = __shfl_xor(bm, o);
    int   oi = __shfl_xor(bi, o);
    if (om > bm || (om == bm && oi < bi)){ bm = om; bi = oi; }
  }
  if (eh == 0){
    u32x2 w;
    w.x = ((c0     == bi) ? 0x3F80u : 0u) | (((c0 + 1 == bi) ? 0x3F80u : 0u) << 16);
    w.y = ((c0 + 2 == bi) ? 0x3F80u : 0u) | (((c0 + 3 == bi) ? 0x3F80u : 0u) << 16);
    *(u32x2*)(y + base + c0) = w;
  }
}

// ---------------- generic MFMA GEMM (packed weights) ----------------
// AMODE 0: A[N,K]; 2: concat(A[N,128], A2[N,32])
// OMODE 0: bf16 out; 3: no store. CSUM: per-block column sums -> pb[blockIdx][128]
template<int K, int DOUT, int CT, int RTW, bool RELU, int AMODE, int OMODE, bool CSUM>
__global__ __launch_bounds__(256) void k_mm(const u16* __restrict__ A, const void* __restrict__ A2,
     const void* __restrict__ A3, const u16* __restrict__ Wp, const float* __restrict__ bp,
     void* __restrict__ outv, const int* __restrict__ flags, float* __restrict__ csacc){
  constexpr int STEPS = K / 32;
  constexpr int G = DOUT / (16 * CT);
  constexpr int CHUNKS = 6250 / RTW;      // N = 6250 * 16 exactly
  __shared__ float lsum[128];
  int wid = blockIdx.x * 4 + (threadIdx.x >> 6);
  if (wid >= G * CHUNKS) return;          // wave-uniform exit
  int g = wid % G; long chunk = wid / G;
  int lane = threadIdx.x & 63, n = lane & 15, q = lane >> 4;
  int colOff = g * CT * 16;

  if (CSUM){
    if (threadIdx.x < 128) lsum[threadIdx.x] = 0.f;
    __syncthreads();
  }

  short8 B[CT][STEPS];
  float bv[CT];
  #pragma unroll
  for (int ct = 0; ct < CT; ++ct){
    int col = colOff + ct * 16 + n;
    bv[ct] = bp[col];
    #pragma unroll
    for (int s = 0; s < STEPS; ++s)
      B[ct][s] = *(const short8*)(Wp + (((s * 4 + q) * DOUT) + col) * 8);
  }

  float csum[CT];
  #pragma unroll
  for (int ct = 0; ct < CT; ++ct) csum[ct] = 0.f;

  for (int rt = 0; rt < RTW; ++rt){
    long rowbase = (chunk * RTW + rt) * 16;
    long arow = rowbase + n;
    v4f acc[CT] = {};
    #pragma unroll
    for (int s = 0; s < STEPS; ++s){
      short8 a;
      if (AMODE == 0){
        a = *(const short8*)(A + arow * K + s * 32 + q * 8);
      } else { // AMODE==2: concat(hemb[N,128], y[N,32]), K=160
        if (s < 4) a = *(const short8*)(A + arow * 128 + s * 32 + q * 8);
        else       a = *(const short8*)((const u16*)A2 + arow * 32 + q * 8);
      }
      #pragma unroll
      for (int ct = 0; ct < CT; ++ct)
        acc[ct] = __builtin_amdgcn_mfma_f32_16x16x32_bf16(a, B[ct][s], acc[ct], 0, 0, 0);
    }
    long orow = rowbase + q * 4;
    #pragma unroll
    for (int ct = 0; ct < CT; ++ct){
      int col = colOff + ct * 16 + n;
      #pragma unroll
      for (int r = 0; r < 4; ++r){
        float v = acc[ct][r] + bv[ct];
        if (RELU) v = fmaxf(v, 0.f);
        if (CSUM) csum[ct] += v;
        if (OMODE != 3){
          long oi = (orow + r) * (long)DOUT + col;
          ((u16*)outv)[oi] = f2b(v);
        }
      }
    }
  }
  if (CSUM){
    #pragma unroll
    for (int ct = 0; ct < CT; ++ct){
      csum[ct] += __shfl_xor(csum[ct], 16);
      csum[ct] += __shfl_xor(csum[ct], 32);
      if (lane < 16) atomicAdd(&lsum[colOff + ct * 16 + n], csum[ct]);
    }
    __syncthreads();
    if (threadIdx.x < 128) csacc[(long)blockIdx.x * 128 + threadIdx.x] = lsum[threadIdx.x];
  }
}

// ---------------- fused h2 GEMM + (h2 @ Why) via LDS: never materializes h2 ----------------
__global__ __launch_bounds__(256) void k_mmh2(const u16* __restrict__ A, const float* __restrict__ AG2,
     const float* __restrict__ zbuf, const u16* __restrict__ Wh2p, const float* __restrict__ bh2p,
     const u16* __restrict__ Whyp, u16* __restrict__ tbuf){
  __shared__ u16 hl[16][200];   // 16x192 bf16 tile, row stride 200 (400B) to break bank conflicts
  int w = threadIdx.x >> 6;
  int lane = threadIdx.x & 63, n = lane & 15, q = lane >> 4;
  int colOff = w * 48;          // 4 waves x CT=3 x 16 = 192 cols

  short8 B[3][6];
  float bv[3];
  #pragma unroll
  for (int ct = 0; ct < 3; ++ct){
    int col = colOff + ct * 16 + n;
    bv[ct] = bh2p[col];
    #pragma unroll
    for (int s = 0; s < 6; ++s)
      B[ct][s] = *(const short8*)(Wh2p + (((s * 4 + q) * 192) + col) * 8);
  }
  short8 B2[2][6];
  if (w == 0){
    #pragma unroll
    for (int ct = 0; ct < 2; ++ct){
      int col = ct * 16 + n;
      #pragma unroll
      for (int s = 0; s < 6; ++s)
        B2[ct][s] = *(const short8*)(Whyp + (((s * 4 + q) * 32) + col) * 8);
    }
  }

  for (int rt = 0; rt < 2; ++rt){
    long rowbase = ((long)blockIdx.x * 2 + rt) * 16;
    long arow = rowbase + n;
    float agr = AG2[arow];
    v4f acc[3] = {};
    #pragma unroll
    for (int s = 0; s < 6; ++s){
      short8 a;
      if (s < 4) a = *(const short8*)(A + arow * 128 + s * 32 + q * 8);
      else {
        #pragma unroll
        for (int j = 0; j < 8; ++j) a[j] = (short)f2b(agr * zbuf[(s - 4) * 32 + q * 8 + j]);
      }
      #pragma unroll
      for (int ct = 0; ct < 3; ++ct)
        acc[ct] = __builtin_amdgcn_mfma_f32_16x16x32_bf16(a, B[ct][s], acc[ct], 0, 0, 0);
    }
    #pragma unroll
    for (int ct = 0; ct < 3; ++ct){
      int col = colOff + ct * 16 + n;
      #pragma unroll
      for (int r = 0; r < 4; ++r)
        hl[q * 4 + r][col] = f2b(fmaxf(acc[ct][r] + bv[ct], 0.f));
    }
    __syncthreads();
    if (w == 0){
      v4f a2[2] = {};
      #pragma unroll
      for (int s = 0; s < 6; ++s){
        short8 a = *(const short8*)(&hl[n][s * 32 + q * 8]);
        #pragma unroll
        for (int ct = 0; ct < 2; ++ct)
          a2[ct] = __builtin_amdgcn_mfma_f32_16x16x32_bf16(a, B2[ct][s], a2[ct], 0, 0, 0);
      }
      #pragma unroll
      for (int ct = 0; ct < 2; ++ct){
        int col = ct * 16 + n;
        #pragma unroll
        for (int r = 0; r < 4; ++r)
          tbuf[(rowbase + q * 4 + r) * 32 + col] = f2b(a2[ct][r]);
      }
    }
    __syncthreads();
  }
}

// ---------------- reduce per-block colsum partials: pb[1563][128] -> accum[128] ----------------
__global__ __launch_bounds__(256) void k_csred(const float* __restrict__ pb, float* __restrict__ accum){
  __shared__ float l[256];
  int c = blockIdx.x, t = threadIdx.x;
  float s = 0.f;
  for (int r = t; r < 1563; r += 256) s += pb[(long)r * 128 + c];
  l[t] = s; __syncthreads();
  for (int o = 128; o; o >>= 1){ if (t < o) l[t] += l[t + o]; __syncthreads(); }
  if (t == 0) accum[c] = l[0];
}

// ---------------- fused (x*dm)@Wxh -> relu -> row-normalize with z -> Hs, AG1 ----------------
__global__ __launch_bounds__(256) void k_mmnorm(const void* __restrict__ A2, const void* __restrict__ A3,
     const u16* __restrict__ Wp, const float* __restrict__ bp,
     u16* __restrict__ outHs, float* __restrict__ ag,
     const float* __restrict__ zbuf, const int* __restrict__ flags){
  constexpr int STEPS = 4, CT = 8, CHUNKS = 6250;   // RTW=1
  int wid = blockIdx.x * 4 + (threadIdx.x >> 6);
  if (wid >= CHUNKS) return;
  long chunk = wid;
  int lane = threadIdx.x & 63, n = lane & 15, q = lane >> 4;
  int fm = flags[0];

  short8 B[CT][STEPS];
  float bv[CT];
  #pragma unroll
  for (int ct = 0; ct < CT; ++ct){
    int col = ct * 16 + n;
    bv[ct] = bp[col];
    #pragma unroll
    for (int s = 0; s < STEPS; ++s)
      B[ct][s] = *(const short8*)(Wp + (((s * 4 + q) * 128) + col) * 8);
  }
  float zz = zbuf[64];

  {
    long rowbase = chunk * 16;
    long arow = rowbase + n;
    v4f acc[CT] = {};
    #pragma unroll
    for (int s = 0; s < STEPS; ++s){
      short8 a;
      long base = arow * 128 + s * 32 + q * 8;
      if (fm){
        const float* xp = (const float*)A2 + base;
        const float* dp = (const float*)A3 + base;
        float4 x0 = *(const float4*)xp, x1 = *(const float4*)(xp + 4);
        float4 d0 = *(const float4*)dp, d1 = *(const float4*)(dp + 4);
        a[0] = (short)f2b(x0.x * d0.x); a[1] = (short)f2b(x0.y * d0.y);
        a[2] = (short)f2b(x0.z * d0.z); a[3] = (short)f2b(x0.w * d0.w);
        a[4] = (short)f2b(x1.x * d1.x); a[5] = (short)f2b(x1.y * d1.y);
        a[6] = (short)f2b(x1.z * d1.z); a[7] = (short)f2b(x1.w * d1.w);
      } else {
        short8 xv = *(const short8*)((const u16*)A2 + base);
        short8 dv = *(const short8*)((const u16*)A3 + base);
        #pragma unroll
        for (int j = 0; j < 8; ++j) a[j] = (short)f2b(b2f((u16)xv[j]) * b2f((u16)dv[j]));
      }
      #pragma unroll
      for (int ct = 0; ct < CT; ++ct)
        acc[ct] = __builtin_amdgcn_mfma_f32_16x16x32_bf16(a, B[ct][s], acc[ct], 0, 0, 0);
    }
    // relu + row-norm epilogue
    float v[CT][4];
    float sqr[4] = {0.f, 0.f, 0.f, 0.f};
    #pragma unroll
    for (int ct = 0; ct < CT; ++ct){
      #pragma unroll
      for (int r = 0; r < 4; ++r){
        float t = fmaxf(acc[ct][r] + bv[ct], 0.f);
        v[ct][r] = t;
        sqr[r] += t * t;
      }
    }
    #pragma unroll
    for (int r = 0; r < 4; ++r){
      #pragma unroll
      for (int o = 1; o < 16; o <<= 1) sqr[r] += __shfl_xor(sqr[r], o);
    }
    float scale[4];
    #pragma unroll
    for (int r = 0; r < 4; ++r) scale[r] = 1.f / (sqrtf(sqr[r] + zz) + 1e-6f);
    long orow = rowbase + q * 4;
    #pragma unroll
    for (int ct = 0; ct < CT; ++ct){
      int col = ct * 16 + n;
      #pragma unroll
      for (int r = 0; r < 4; ++r)
        outHs[(orow + r) * 128 + col] = f2b(v[ct][r] * scale[r]);
    }
    if (n == 0){
      #pragma unroll
      for (int r = 0; r < 4; ++r) ag[orow + r] = scale[r];
    }
  }
}

// ---------------- tiny tail: r_graph -> hr -> mu/sigma -> z, plus ||z||^2 ----------------
__global__ void k_z(const float* __restrict__ accum,
                    const void* Whr, const void* bhr, const void* Wrh, const void* brh,
                    const void* Wmu, const void* bmu, const void* Wsig, const void* bsig,
                    const void* zeps, float* __restrict__ zout, const int* __restrict__ flags){
  __shared__ float hm[128], rg[128], hr[128], zl[64];
  int t = threadIdx.x, fm = flags[0];
  hm[t] = accum[t] * (1.0f / 100000.0f);
  __syncthreads();
  { float s = ldx(bhr, t, fm);
    for (int k = 0; k < 128; ++k) s = fmaf(hm[k], ldx(Whr, (long)k * 128 + t, fm), s);
    rg[t] = s; }
  __syncthreads();
  { float s = ldx(brh, t, fm);
    for (int k = 0; k < 128; ++k) s = fmaf(rg[k], ldx(Wrh, (long)k * 128 + t, fm), s);
    hr[t] = fmaxf(s, 0.f); }
  __syncthreads();
  if (t < 64){
    float m = ldx(bmu, t, fm), sv = ldx(bsig, t, fm);
    for (int k = 0; k < 128; ++k){
      float h = hr[k];
      m  = fmaf(h, ldx(Wmu,  (long)k * 64 + t, fm), m);
      sv = fmaf(h, ldx(Wsig, (long)k * 64 + t, fm), sv);
    }
    float sig = 0.1f + 0.9f / (1.f + expf(-sv));
    float z = fmaf(sig, ldx(zeps, t, fm), m);
    zl[t] = z; zout[t] = z;
  }
  __syncthreads();
  if (t == 0){ float ss = 0.f; for (int j = 0; j < 64; ++j) ss += zl[j] * zl[j]; zout[64] = ss; }
}

extern "C" void kernel_launch(void* const* d_in, const int* in_sizes, int n_in,
                              void* d_out, int out_size, void* d_ws, size_t ws_size,
                              hipStream_t stream){
  const void* x    = d_in[0];
  const void* ylab = d_in[1];
  const int*  ei   = (const int*)d_in[2];
  const void* ew   = d_in[3];
  const void* nonlab = d_in[4];
  const void* dm   = d_in[5];
  const void* ug   = d_in[6];
  const void* zeps = d_in[7];
  const void* Wg1 = d_in[8],  *bg1 = d_in[9];
  const void* Wg2 = d_in[10], *bg2 = d_in[11];
  const void* Wxy = d_in[12], *bxy = d_in[13];
  const void* Whr = d_in[14], *bhr = d_in[15];
  const void* Wrh = d_in[16], *brh = d_in[17];
  const void* Wmu = d_in[18], *bmu = d_in[19];
  const void* Wsg = d_in[20], *bsg = d_in[21];
  const void* Wxh = d_in[22], *bxh = d_in[23];
  const void* Wh2 = d_in[24], *bh2 = d_in[25];
  const void* Why = d_in[26], *bhy = d_in[27];

  char* ws = (char*)d_ws;
  size_t off = 0;
  auto alloc = [&](size_t bytes){ void* p = ws + off; off += (bytes + 511) & ~(size_t)511; return p; };
  int*   flags  = (int*)  alloc(256);
  int*   rowptr = (int*)  alloc((size_t)(NN + 1) * 4);
  float* accum  = (float*)alloc(1024 * 4);   // [0:128) colsum, [128:192) z, [192] ||z||^2, [512:708) bcnt
  u16*   Wpack  = (u16*)  alloc((size_t)PW_TOT * 2);
  float* bpack  = (float*)alloc((size_t)PB_TOT * 4);
  float* AG1    = (float*)alloc((size_t)NN * 4);   // per-row norm scale
  float* AG2    = (float*)alloc((size_t)NN * 4);   // spmm of scale
  float* pb     = (float*)alloc((size_t)1563 * 128 * 4);  // per-block colsum partials
  int2*  cpk    = (int2*) alloc((size_t)EE * 8);
  u16*   B0     = (u16*)  alloc((size_t)NN * 192 * 2);
  u16*   B1     = (u16*)  alloc((size_t)NN * 192 * 2);
  // layout: stage=B0 (dead after binB); xp=B1[0:128] (dead after S1); h_emb=B0[0:128];
  // yproj=B0[128:160); ybuf=B1[160:192); Hs=B1[0:128]; tbuf(bf16)=B1[0:32) (B0 live as spmmH!)
  u16* yproj = B0 + (size_t)NN * 128;   // [N,32] bf16 (h_emb @ Wg2)
  u16* ybuf  = B1 + (size_t)NN * 160;   // [N,32] bf16 (y)
  int2* stage = (int2*)B0;
  u16* tbuf = B1;                       // [N,32] bf16 (h2 @ Why) -- B1 free after S3 consumed Hs
  int* bcnt = (int*)(accum + 512);      // NBK per-bucket staged counts (zeroed by k_pack)

  // pack (+detect +accum zero) -- must precede everything that reads flags/bcnt/Wpack
  k_pack<<<(PW_TOT + PB_TOT + 255) / 256, 256, 0, stream>>>(Wg1, Wg2, Wxy, Wxh, Wh2, Why,
                                                            bg1, bxy, bxh, bh2, bhy, Wpack, bpack,
                                                            x, nonlab, flags, accum);
  // mega-kernel: xp GEMM (1563 blocks) overlapped with binA (391 blocks)
  k_front<<<1954, 256, 0, stream>>>(x, Wpack + PW_G1, B1, flags, ei, ew, bcnt, stage);
  k_binB <<<NBK, 512, 0, stream>>>(bcnt, stage, cpk, rowptr);   // scanB folded in (self prefix)
  // pipeline
  k_spmm<false,true ><<<25000, 256, 0, stream>>>(B1, B0, rowptr, cpk, nullptr, nullptr, bpack + PB_G1); // S1: h_emb -> B0
  k_mm<128,32 ,2,1,false,0,0,false><<<1563, 256, 0, stream>>>(B0, nullptr, nullptr, Wpack + PW_G2, bpack + PB_ZERO, yproj, flags, nullptr); // yproj = h_emb@Wg2
  k_spmmg<<<6250, 256, 0, stream>>>(yproj, ybuf, rowptr, cpk, flags, bg2, ug, ylab, nonlab);     // S2'+gumbel -> y
  k_mm<160,128,4,2,true ,2,3,true ><<<1563, 256, 0, stream>>>(B0, ybuf, nullptr, Wpack + PW_XY, bpack + PB_XY, nullptr, flags, pb); // colsum partials
  k_csred<<<128, 256, 0, stream>>>(pb, accum);                                                   // reduce -> accum[0:128)
  k_z<<<1, 128, 0, stream>>>(accum, Whr, bhr, Wrh, brh, Wmu, bmu, Wsg, bsg, zeps, accum + 128, flags);
  k_mmnorm<<<1563, 256, 0, stream>>>(x, dm, Wpack + PW_XH, bpack + PB_XH, B1, AG1, accum + 128, flags); // Hs->B1, AG1
  k_spmm<true ,false><<<25000, 256, 0, stream>>>(B1, B0, rowptr, cpk, AG1, AG2, nullptr);        // S3: Hs->B0, agg->AG2
  k_mmh2<<<3125, 256, 0, stream>>>(B0, AG2, accum + 128, Wpack + PW_H2, bpack + PB_H2,
                                   Wpack + PW_HY, tbuf);                                         // fused h2+Why -> tbuf (B1)
  k_spmm32b<<<6250, 256, 0, stream>>>(tbuf, d_out, rowptr, cpk, flags, bpack + PB_HY);           // S4': y_pred
}